// Round 4
// baseline (305.208 us; speedup 1.0000x reference)
//
#include <hip/hip_runtime.h>
#include <cstdint>
#include <cstddef>

// ---------------- problem constants ----------------
#define B_    16
#define L_    2048
#define H_    768
#define NE_   64
#define SPAN_ 4
#define NPAIR 2016              // 64*63/2
#define NROWS (B_ * NPAIR)      // 32256 = 504 * 64

typedef __bf16 bf16_t;
typedef __bf16 bf16x8 __attribute__((ext_vector_type(8)));
typedef __bf16 bf16x4 __attribute__((ext_vector_type(4)));
typedef float  floatx4 __attribute__((ext_vector_type(4)));

// ---------------- ws layout (bytes, all 256-aligned) ----------------
#define OFF_EMBH   ((size_t)3145728)
#define OFF_SIM    ((size_t)8126464)
#define OFF_W1ABT  ((size_t)8255488)
#define OFF_W2T    ((size_t)10614784)
#define OFF_W3T    ((size_t)11401216)
#define OFF_C1     ((size_t)11663360)
#define OFF_H2     ((size_t)67500032)
#define OFF_FLAG   ((size_t)117045248)
#define OFF_CANON  ((size_t)117045504)
// canon bf16: [0:768) w1row0, [768:1536) b1, [1536:2048) b2,
//             [2048:2304) b3, [2304:2816) w4, [2816:2818) b4

__device__ inline bf16_t cvt_elem(const void* p, size_t i, int isf) {
  if (isf) return (bf16_t)(((const float*)p)[i]);
  return ((const bf16_t*)p)[i];
}

// ---------------- K0 (merged): flag + canon + weight transposes + embsim ----
// grid 433 x 1024 threads.
//   blocks 0..15   : fused span max-pool + norm + MFMA cosine + std + sim
//   block  16      : canon pack + flag store
//   blocks 17..432 : 64x64 LDS-tiled weight transposes (w1a/w1b/w2/w3)
__global__ __launch_bounds__(1024) void prep_embsim_kernel(
    const unsigned short* __restrict__ xu,          // == x, for flag scan
    const void* __restrict__ xv, const int* __restrict__ starts,
    const void* __restrict__ thr_ptr,
    const void* __restrict__ w1, const void* __restrict__ w2,
    const void* __restrict__ w3, const void* __restrict__ b1,
    const void* __restrict__ b2, const void* __restrict__ b3,
    const void* __restrict__ w4, const void* __restrict__ b4,
    int* __restrict__ flagout,
    bf16_t* __restrict__ w1abT, bf16_t* __restrict__ w2T,
    bf16_t* __restrict__ w3T, bf16_t* __restrict__ canon,
    bf16_t* __restrict__ embh, float* __restrict__ simv) {
  __shared__ __align__(16) char shbuf[98304];       // 96 KB: nrm / tile union
  __shared__ int   tot[16];
  __shared__ float red1[16], red2[16];
  __shared__ float scale_s, thr_s;

  int blk = blockIdx.x;
  int t = threadIdx.x;

  // ---- inline dtype flag (uniform across all blocks) ----
  {
    int bad = 0;
    for (int i = t; i < 4096; i += 1024) {
      int e = (xu[i] >> 7) & 0xFF;
      if (e > 133 || (e > 0 && e < 90)) bad++;
    }
    for (int off = 32; off > 0; off >>= 1) bad += __shfl_down(bad, off, 64);
    if ((t & 63) == 0) tot[t >> 6] = bad;
    __syncthreads();
  }
  int sumb = 0;
#pragma unroll
  for (int i = 0; i < 16; i++) sumb += tot[i];
  int isf = (sumb > 200) ? 1 : 0;
  __syncthreads();

  if (blk < 16) {
    // ================= embsim =================
    bf16_t* nrm = (bf16_t*)shbuf;                   // 64 x 768, xor-swizzled
    int b = blk;
    // ---- phase 1: span max-pool + norm ----
    int e   = t >> 4;            // entity 0..63
    int l16 = t & 15;
    int d0  = l16 * 48;
    int st  = starts[b * NE_ + e];
    size_t off = ((size_t)(b * L_ + st)) * H_;
    float ss = 0.f;
    bf16x8 pv[6];
    if (isf) {
      const float* xp = (const float*)xv + off + d0;
#pragma unroll
      for (int c8 = 0; c8 < 6; c8++) {
        const float* p = xp + c8 * 8;
        bf16x8 o;
#pragma unroll
        for (int h = 0; h < 2; h++) {
          floatx4 r0 = *(const floatx4*)(p + h * 4);
          floatx4 r1 = *(const floatx4*)(p + H_ + h * 4);
          floatx4 r2 = *(const floatx4*)(p + 2 * H_ + h * 4);
          floatx4 r3 = *(const floatx4*)(p + 3 * H_ + h * 4);
#pragma unroll
          for (int q = 0; q < 4; q++) {
            float v = fmaxf(fmaxf(r0[q], r1[q]), fmaxf(r2[q], r3[q]));
            ss += v * v;
            o[h * 4 + q] = (bf16_t)v;
          }
        }
        pv[c8] = o;
      }
    } else {
      const bf16_t* xp = (const bf16_t*)xv + off + d0;
#pragma unroll
      for (int c8 = 0; c8 < 6; c8++) {
        const bf16_t* p = xp + c8 * 8;
        bf16x8 r0 = *(const bf16x8*)(p);
        bf16x8 r1 = *(const bf16x8*)(p + H_);
        bf16x8 r2 = *(const bf16x8*)(p + 2 * H_);
        bf16x8 r3 = *(const bf16x8*)(p + 3 * H_);
        bf16x8 o;
#pragma unroll
        for (int q = 0; q < 8; q++) {
          float v = fmaxf(fmaxf((float)r0[q], (float)r1[q]),
                          fmaxf((float)r2[q], (float)r3[q]));
          ss += v * v;
          o[q] = (bf16_t)v;
        }
        pv[c8] = o;
      }
    }
#pragma unroll
    for (int d = 1; d < 16; d <<= 1) ss += __shfl_xor(ss, d, 64);
    float inv = 1.0f / fmaxf(sqrtf(ss), 1e-8f);

    size_t gb = ((size_t)(b * 64 + e)) * 768 + d0;
    int rowbyte = e * 1536;
    int xw = (e & 7) << 4;
#pragma unroll
    for (int c8 = 0; c8 < 6; c8++) {
      *(bf16x8*)(embh + gb + c8 * 8) = pv[c8];
      bf16x8 o;
#pragma unroll
      for (int q = 0; q < 8; q++) o[q] = (bf16_t)((float)pv[c8][q] * inv);
      int byo = (rowbyte + (d0 + c8 * 8) * 2) ^ xw;
      *(bf16x8*)((char*)nrm + byo) = o;
    }
    __syncthreads();

    // ---- phase 2: cos tiles via MFMA (16 waves = 4x4 tiles) ----
    int w = t >> 6, lane = t & 63;
    int quad = lane >> 4, l15 = lane & 15;
    int ti = w >> 2, tj = w & 3;
    int rowA = ti * 16 + l15, rowB = tj * 16 + l15;
    int xa = (rowA & 7) << 4, xb = (rowB & 7) << 4;
    const char* nb = (const char*)nrm;
    floatx4 acc = {};
#pragma unroll 4
    for (int k0 = 0; k0 < 768; k0 += 32) {
      int cb = (k0 + quad * 8) * 2;
      bf16x8 aF = *(const bf16x8*)(nb + ((rowA * 1536 + cb) ^ xa));
      bf16x8 bF = *(const bf16x8*)(nb + ((rowB * 1536 + cb) ^ xb));
      acc = __builtin_amdgcn_mfma_f32_16x16x32_bf16(aF, bF, acc, 0, 0, 0);
    }

    // ---- phase 3: mean/var (ddof=1) + sim ----
    float s1 = acc[0] + acc[1] + acc[2] + acc[3];
    float s2 = acc[0] * acc[0] + acc[1] * acc[1] + acc[2] * acc[2] + acc[3] * acc[3];
#pragma unroll
    for (int d = 32; d > 0; d >>= 1) {
      s1 += __shfl_xor(s1, d, 64);
      s2 += __shfl_xor(s2, d, 64);
    }
    if (lane == 0) { red1[w] = s1; red2[w] = s2; }
    __syncthreads();
    if (t == 0) {
      float S1 = 0.f, S2 = 0.f;
#pragma unroll
      for (int i = 0; i < 16; i++) { S1 += red1[i]; S2 += red2[i]; }
      float mean = S1 * (1.0f / 4096.0f);
      float var = (S2 - 4096.0f * mean * mean) * (1.0f / 4095.0f);
      float sd = sqrtf(fmaxf(var, 0.f));
      scale_s = 1.0f / (sd + 1e-5f);
      thr_s = isf ? *(const float*)thr_ptr : (float)(*(const bf16_t*)thr_ptr);
    }
    __syncthreads();
    float sc = scale_s, th = thr_s;
    int ibase = ti * 16 + quad * 4;
    int j = tj * 16 + l15;
#pragma unroll
    for (int r = 0; r < 4; r++) {
      int i = ibase + r;
      if (j > i) {
        int p = i * 63 - (i * (i - 1)) / 2 + (j - i - 1);
        simv[b * NPAIR + p] = (acc[r] - th) * sc;
      }
    }
    return;
  }

  if (blk == 16) {
    // ================= canon + flag =================
    if (t == 0) flagout[0] = isf;
    for (int idx = t; idx < 2818; idx += 1024) {
      if (idx < 768)       canon[idx] = cvt_elem(w1, idx, isf);
      else if (idx < 1536) canon[idx] = cvt_elem(b1, idx - 768, isf);
      else if (idx < 2048) canon[idx] = cvt_elem(b2, idx - 1536, isf);
      else if (idx < 2304) canon[idx] = cvt_elem(b3, idx - 2048, isf);
      else if (idx < 2816) canon[idx] = cvt_elem(w4, idx - 2304, isf);
      else                 canon[idx] = cvt_elem(b4, idx - 2816, isf);
    }
    return;
  }

  // ================= 64x64 weight transpose =================
  int tix = blk - 17;
  const void* src; size_t srcoff; bf16_t* dst; int K, N;
  if (tix < 144)      { src = w1; srcoff = 768;               dst = w1abT;          K = 768; N = 768; }
  else if (tix < 288) { src = w1; srcoff = (size_t)769 * 768; dst = w1abT + 589824; K = 768; N = 768; tix -= 144; }
  else if (tix < 384) { src = w2; srcoff = 0;                 dst = w2T;            K = 768; N = 512; tix -= 288; }
  else                { src = w3; srcoff = 0;                 dst = w3T;            K = 512; N = 256; tix -= 384; }
  int tiles_k = K >> 6;
  int tn_t = tix / tiles_k, tk_t = tix - tn_t * tiles_k;
  bf16_t (*tile)[65] = (bf16_t(*)[65])shbuf;      // 64x65 bf16 = 8.3 KB
  int ty = t >> 6, tx = t & 63;
#pragma unroll
  for (int p = 0; p < 4; p++) {
    int kk = tk_t * 64 + p * 16 + ty;
    int nn = tn_t * 64 + tx;
    tile[p * 16 + ty][tx] = cvt_elem(src, srcoff + (size_t)kk * N + nn, isf);
  }
  __syncthreads();
#pragma unroll
  for (int p = 0; p < 4; p++) {
    int nn = tn_t * 64 + p * 16 + ty;
    int kk = tk_t * 64 + tx;
    dst[(size_t)nn * K + kk] = tile[tx][p * 16 + ty];
  }
}

// ---------------- K1: bf16 MFMA GEMM1, 64x128 tiles (192 blocks) ----------
__global__ __launch_bounds__(256) void gemm1_kernel(
    const bf16_t* __restrict__ A, const bf16_t* __restrict__ Bt,
    float* __restrict__ C) {
  const int K = 768, N = 1536;
  __shared__ __align__(16) bf16_t Asm[64 * 32];    // 4 KB
  __shared__ __align__(16) bf16_t Bsm[128 * 32];   // 8 KB
  int bm = blockIdx.x, bn = blockIdx.y;
  int t = threadIdx.x;
  int w = t >> 6, lane = t & 63;
  int quad = lane >> 4, l15 = lane & 15;
  int wm = w >> 1, wn = w & 1;                     // 2x2 waves, wave = 32x64

  floatx4 acc[2][4] = {};
  const char* Abase = (const char*)(A + (size_t)bm * 64 * K);
  const char* Bbase = (const char*)(Bt + (size_t)bn * 128 * K);
  const int rowbytes = K * 2;

  for (int k0 = 0; k0 < K; k0 += 32) {
    {   // A: 4 KB, wave-contiguous 1 KB regions
      int fo = w * 1024 + lane * 16;
      int row = fo >> 6, colb = fo & 63;
      __builtin_amdgcn_global_load_lds(
          (__attribute__((address_space(1))) char*)(Abase + (size_t)row * rowbytes + k0 * 2 + colb),
          (__attribute__((address_space(3))) char*)((char*)Asm + w * 1024),
          16, 0, 0);
    }
#pragma unroll
    for (int it = 0; it < 2; it++) {   // B: 8 KB
      int fo = (w * 2 + it) * 1024 + lane * 16;
      int row = fo >> 6, colb = fo & 63;
      __builtin_amdgcn_global_load_lds(
          (__attribute__((address_space(1))) char*)(Bbase + (size_t)row * rowbytes + k0 * 2 + colb),
          (__attribute__((address_space(3))) char*)((char*)Bsm + (w * 2 + it) * 1024),
          16, 0, 0);
    }
    __syncthreads();

    bf16x8 aF[2], bF[4];
#pragma unroll
    for (int tm = 0; tm < 2; tm++)
      aF[tm] = *((const bf16x8*)(Asm + (wm * 32 + tm * 16 + l15) * 32 + quad * 8));
#pragma unroll
    for (int tn = 0; tn < 4; tn++)
      bF[tn] = *((const bf16x8*)(Bsm + (wn * 64 + tn * 16 + l15) * 32 + quad * 8));
#pragma unroll
    for (int tm = 0; tm < 2; tm++)
#pragma unroll
      for (int tn = 0; tn < 4; tn++)
        acc[tm][tn] = __builtin_amdgcn_mfma_f32_16x16x32_bf16(aF[tm], bF[tn], acc[tm][tn], 0, 0, 0);
    __syncthreads();
  }

#pragma unroll
  for (int tm = 0; tm < 2; tm++) {
    int grow0 = bm * 64 + wm * 32 + tm * 16 + quad * 4;
#pragma unroll
    for (int tn = 0; tn < 4; tn++) {
      int gcol = bn * 128 + wn * 64 + tn * 16 + l15;
#pragma unroll
      for (int r = 0; r < 4; r++)
        C[(size_t)(grow0 + r) * N + gcol] = acc[tm][tn][r];
    }
  }
}

// ---------------- K2: fused GEMM2 + GEMM3 + final, 64-row full-width ------
// grid 504, 512 thr / 8 waves (2x4).
// layer2: tile 64 x 512 (full N), K=768; h1 assembled on the fly from C1;
//         h2 tile written to GLOBAL (stays L2-hot, own rows only).
// layer3: tile 64 x 256 (full N), K=512; A re-staged from own h2 rows (L2).
// LDS ~48 KB -> 3 blocks/CU capacity; grid 504 -> ~2 resident/CU.
__global__ __launch_bounds__(512) void gemm23_kernel(
    const float* __restrict__ C1, const float* __restrict__ sim,
    const bf16_t* __restrict__ w2T, const bf16_t* __restrict__ w3T,
    const bf16_t* __restrict__ canon, const int* __restrict__ flagp,
    bf16_t* __restrict__ h2, void* __restrict__ out) {
  __shared__ __align__(16) bf16_t Asm[64 * 40];    // 5 KB; reused: layer3 A [64][32]
  __shared__ __align__(16) bf16_t Bsm[512 * 32];   // 32 KB; reused: w3T buf (16 KB)
  __shared__ int   rowI[64], rowJ[64];
  __shared__ float rowS[64];
  __shared__ bf16_t w1s[768], b1s[768];
  __shared__ float b2s[512];
  __shared__ float b3s[256];
  __shared__ float w4s[512];
  __shared__ float part[64][2][4];
  int bm = blockIdx.x;
  int t = threadIdx.x;

  if (t < 64) {
    int r = bm * 64 + t;
    int b = r / NPAIR, p = r - b * NPAIR;
    int i = 0, rem = p;
    while (rem >= 63 - i) { rem -= 63 - i; i++; }
    rowI[t] = b * 64 + i;
    rowJ[t] = b * 64 + i + 1 + rem;
    rowS[t] = sim[r];
  }
  for (int c = t; c < 768; c += 512) { w1s[c] = canon[c]; b1s[c] = canon[768 + c]; }
  b2s[t] = (float)canon[1536 + t];
  if (t < 256) b3s[t] = (float)canon[2048 + t];
  w4s[t] = (float)canon[2304 + t];
  __syncthreads();

  int w = t >> 6, lane = t & 63;
  int quad = lane >> 4, l15 = lane & 15;
  int wm = w >> 2, wn = w & 3;                     // 2x4 waves, wave = 32x128

  // ---------- layer 2: h2(own 64 rows, all 512 cols) ----------
  floatx4 acc[2][8] = {};
  int arow = t >> 3;             // 0..63
  int acolc = (t & 7) * 4;       // 0,4,...,28
  const float* Ai = C1 + (size_t)rowI[arow] * 1536 + acolc;
  const float* Aj = C1 + (size_t)rowJ[arow] * 1536 + 768 + acolc;
  float s = rowS[arow];
  bf16_t* awr = Asm + arow * 40 + acolc;

  float4 pi = *(const float4*)(Ai);
  float4 pj = *(const float4*)(Aj);

  for (int k0 = 0; k0 < 768; k0 += 32) {
    // B staging: 32 KB (512 rows x 64 B), wave-contiguous 4 KB regions
#pragma unroll
    for (int it = 0; it < 4; it++) {
      int fo = w * 4096 + it * 1024 + lane * 16;
      int row = fo >> 6, colb = fo & 63;
      __builtin_amdgcn_global_load_lds(
          (__attribute__((address_space(1))) char*)((const char*)w2T + (size_t)row * 1536 + k0 * 2 + colb),
          (__attribute__((address_space(3))) char*)((char*)Bsm + w * 4096 + it * 1024),
          16, 0, 0);
    }
    // A: assemble 4 bf16 from prefetched regs, one ds_write_b64
    {
      int kc = k0 + acolc;
      bf16x4 o;
      o[0] = (bf16_t)fmaxf(pi.x + pj.x + s * (float)w1s[kc]     + (float)b1s[kc],     0.f);
      o[1] = (bf16_t)fmaxf(pi.y + pj.y + s * (float)w1s[kc + 1] + (float)b1s[kc + 1], 0.f);
      o[2] = (bf16_t)fmaxf(pi.z + pj.z + s * (float)w1s[kc + 2] + (float)b1s[kc + 2], 0.f);
      o[3] = (bf16_t)fmaxf(pi.w + pj.w + s * (float)w1s[kc + 3] + (float)b1s[kc + 3], 0.f);
      *(bf16x4*)awr = o;
    }
    if (k0 + 32 < 768) {
      pi = *(const float4*)(Ai + k0 + 32);
      pj = *(const float4*)(Aj + k0 + 32);
    }
    __syncthreads();

    bf16x8 aF[2], bF[8];
#pragma unroll
    for (int tm = 0; tm < 2; tm++)
      aF[tm] = *((const bf16x8*)(Asm + (wm * 32 + tm * 16 + l15) * 40 + quad * 8));
#pragma unroll
    for (int tn = 0; tn < 8; tn++)
      bF[tn] = *((const bf16x8*)(Bsm + (wn * 128 + tn * 16 + l15) * 32 + quad * 8));
#pragma unroll
    for (int tm = 0; tm < 2; tm++)
#pragma unroll
      for (int tn = 0; tn < 8; tn++)
        acc[tm][tn] = __builtin_amdgcn_mfma_f32_16x16x32_bf16(aF[tm], bF[tn], acc[tm][tn], 0, 0, 0);
    __syncthreads();
  }

  // h2 epilogue: bias + relu -> bf16, global (own rows; L2-hot for layer 3)
#pragma unroll
  for (int tm = 0; tm < 2; tm++) {
#pragma unroll
    for (int tn = 0; tn < 8; tn++) {
      int col = wn * 128 + tn * 16 + l15;
#pragma unroll
      for (int r = 0; r < 4; r++) {
        int row = wm * 32 + tm * 16 + quad * 4 + r;
        float v = fmaxf(acc[tm][tn][r] + b2s[col], 0.f);
        h2[((size_t)bm * 64 + row) * 512 + col] = (bf16_t)v;
      }
    }
  }
  __syncthreads();   // drains the h2 stores (vmcnt 0) before re-read

  // ---------- layer 3: h3 = relu(h2 @ w3 + b3) on own rows ----------
  floatx4 acc2[2][4] = {};
  const char* Abase3 = (const char*)(h2 + (size_t)bm * 64 * 512);
  for (int k0 = 0; k0 < 512; k0 += 32) {
    if (w < 4) {   // A: 4 KB (64 rows x 64 B), waves 0-3
      int fo = w * 1024 + lane * 16;
      int row = fo >> 6, colb = fo & 63;
      __builtin_amdgcn_global_load_lds(
          (__attribute__((address_space(1))) char*)(Abase3 + (size_t)row * 1024 + k0 * 2 + colb),
          (__attribute__((address_space(3))) char*)((char*)Asm + w * 1024),
          16, 0, 0);
    }
#pragma unroll
    for (int it = 0; it < 2; it++) {   // B (w3T): 16 KB (256 rows x 64 B)
      int fo = w * 2048 + it * 1024 + lane * 16;
      int row = fo >> 6, colb = fo & 63;
      __builtin_amdgcn_global_load_lds(
          (__attribute__((address_space(1))) char*)((const char*)w3T + (size_t)row * 1024 + k0 * 2 + colb),
          (__attribute__((address_space(3))) char*)((char*)Bsm + w * 2048 + it * 1024),
          16, 0, 0);
    }
    __syncthreads();

    bf16x8 aF[2], bF[4];
#pragma unroll
    for (int tm = 0; tm < 2; tm++)
      aF[tm] = *((const bf16x8*)(Asm + (wm * 32 + tm * 16 + l15) * 32 + quad * 8));
#pragma unroll
    for (int tn = 0; tn < 4; tn++)
      bF[tn] = *((const bf16x8*)(Bsm + (wn * 64 + tn * 16 + l15) * 32 + quad * 8));
#pragma unroll
    for (int tm = 0; tm < 2; tm++)
#pragma unroll
      for (int tn = 0; tn < 4; tn++)
        acc2[tm][tn] = __builtin_amdgcn_mfma_f32_16x16x32_bf16(aF[tm], bF[tn], acc2[tm][tn], 0, 0, 0);
    __syncthreads();
  }

  // ---------- final: relu+b3, w4 reduce, b4 ----------
#pragma unroll
  for (int tm = 0; tm < 2; tm++) {
#pragma unroll
    for (int reg = 0; reg < 4; reg++) {
      float p0 = 0.f, p1 = 0.f;
#pragma unroll
      for (int tn = 0; tn < 4; tn++) {
        int col = wn * 64 + tn * 16 + l15;
        float v = fmaxf(acc2[tm][tn][reg] + b3s[col], 0.f);
        p0 += v * w4s[col * 2];
        p1 += v * w4s[col * 2 + 1];
      }
#pragma unroll
      for (int d = 1; d < 16; d <<= 1) {
        p0 += __shfl_xor(p0, d, 64);
        p1 += __shfl_xor(p1, d, 64);
      }
      if (l15 == 0) {
        int r = wm * 32 + tm * 16 + quad * 4 + reg;
        part[r][0][wn] = p0;
        part[r][1][wn] = p1;
      }
    }
  }
  __syncthreads();
  if (t < 128) {
    int r = t >> 1, c = t & 1;
    float v = part[r][c][0] + part[r][c][1] + part[r][c][2] + part[r][c][3]
            + (float)canon[2816 + c];
    size_t rg = (size_t)bm * 64 + r;
    if (flagp[0]) ((float*)out)[rg * 2 + c] = v;
    else          ((bf16_t*)out)[rg * 2 + c] = (bf16_t)v;
  }
}

// ---------------- launch ----------------
extern "C" void kernel_launch(void* const* d_in, const int* in_sizes, int n_in,
                              void* d_out, int out_size, void* d_ws, size_t ws_size,
                              hipStream_t stream) {
  const void* x      = d_in[0];
  const void* thr    = d_in[1];
  const void* w1     = d_in[2];
  const void* b1     = d_in[3];
  const void* w2     = d_in[4];
  const void* b2     = d_in[5];
  const void* w3     = d_in[6];
  const void* b3     = d_in[7];
  const void* w4     = d_in[8];
  const void* b4     = d_in[9];
  const int*  starts = (const int*)d_in[10];

  char* ws = (char*)d_ws;
  bf16_t* embh  = (bf16_t*)(ws + OFF_EMBH);
  float*  simv  = (float*)(ws + OFF_SIM);
  bf16_t* w1abT = (bf16_t*)(ws + OFF_W1ABT);
  bf16_t* w2T   = (bf16_t*)(ws + OFF_W2T);
  bf16_t* w3T   = (bf16_t*)(ws + OFF_W3T);
  float*  C1    = (float*)(ws + OFF_C1);
  bf16_t* h2    = (bf16_t*)(ws + OFF_H2);
  int*    flag  = (int*)(ws + OFF_FLAG);
  bf16_t* canon = (bf16_t*)(ws + OFF_CANON);

  // merged: flag + canon + transposes + (span max-pool / cosine / std / sim)
  prep_embsim_kernel<<<433, 1024, 0, stream>>>(
      (const unsigned short*)x, x, starts, thr,
      w1, w2, w3, b1, b2, b3, w4, b4,
      flag, w1abT, w2T, w3T, canon, embh, simv);

  // C1 = emb @ [W1a | W1b] : [1024,768] x [768,1536] -> fp32
  {
    dim3 g(1024 / 64, 1536 / 128);
    gemm1_kernel<<<g, 256, 0, stream>>>(embh, w1abT, C1);
  }

  // fused layers 2+3+4: full-width 64-row tiles, h2 round-trips via L2
  gemm23_kernel<<<NROWS / 64, 512, 0, stream>>>(C1, simv, w2T, w3T, canon,
                                                flag, h2, d_out);
}

// Round 5
// 269.424 us; speedup vs baseline: 1.1328x; 1.1328x over previous
//
#include <hip/hip_runtime.h>
#include <cstdint>
#include <cstddef>

// ---------------- problem constants ----------------
#define B_    16
#define L_    2048
#define H_    768
#define NE_   64
#define SPAN_ 4
#define NPAIR 2016              // 64*63/2
#define NROWS (B_ * NPAIR)      // 32256 = 252 * 128

typedef __bf16 bf16_t;
typedef __bf16 bf16x8 __attribute__((ext_vector_type(8)));
typedef __bf16 bf16x4 __attribute__((ext_vector_type(4)));
typedef float  floatx4 __attribute__((ext_vector_type(4)));

// ---------------- ws layout (bytes, all 256-aligned) ----------------
#define OFF_EMBH   ((size_t)3145728)
#define OFF_SIM    ((size_t)8126464)
#define OFF_W1ABT  ((size_t)8255488)
#define OFF_W2T    ((size_t)10614784)
#define OFF_W3T    ((size_t)11401216)
#define OFF_C1     ((size_t)11663360)
#define OFF_H2     ((size_t)67500032)
#define OFF_FLAG   ((size_t)117045248)
#define OFF_CANON  ((size_t)117045504)
// canon bf16: [0:768) w1row0, [768:1536) b1, [1536:2048) b2,
//             [2048:2304) b3, [2304:2816) w4, [2816:2818) b4

// T2 both-sides swizzle (rule #21): gload_lds writes linearly, so the
// permutation is applied to the GLOBAL source byte-in-row (colb ^ x) and the
// identical XOR is applied on the ds_read side. x = (row&3)<<4 stays inside
// the 64B row chunk. Turns the 8-way row*64 bank conflict into ~4-way.
#define SWZ(colb, row) ((colb) ^ (((row) & 3) << 4))

__device__ inline bf16_t cvt_elem(const void* p, size_t i, int isf) {
  if (isf) return (bf16_t)(((const float*)p)[i]);
  return ((const bf16_t*)p)[i];
}

// ---------------- K0 (merged): flag + canon + weight transposes + embsim ----
// grid 433 x 1024 threads.
//   blocks 0..15   : fused span max-pool + norm + MFMA cosine + std + sim
//   block  16      : canon pack + flag store
//   blocks 17..432 : 64x64 LDS-tiled weight transposes (w1a/w1b/w2/w3)
__global__ __launch_bounds__(1024) void prep_embsim_kernel(
    const unsigned short* __restrict__ xu,          // == x, for flag scan
    const void* __restrict__ xv, const int* __restrict__ starts,
    const void* __restrict__ thr_ptr,
    const void* __restrict__ w1, const void* __restrict__ w2,
    const void* __restrict__ w3, const void* __restrict__ b1,
    const void* __restrict__ b2, const void* __restrict__ b3,
    const void* __restrict__ w4, const void* __restrict__ b4,
    int* __restrict__ flagout,
    bf16_t* __restrict__ w1abT, bf16_t* __restrict__ w2T,
    bf16_t* __restrict__ w3T, bf16_t* __restrict__ canon,
    bf16_t* __restrict__ embh, float* __restrict__ simv) {
  __shared__ __align__(16) char shbuf[98304];       // 96 KB: nrm / tile union
  __shared__ int   tot[16];
  __shared__ float red1[16], red2[16];
  __shared__ float scale_s, thr_s;

  int blk = blockIdx.x;
  int t = threadIdx.x;

  // ---- inline dtype flag (uniform across all blocks) ----
  {
    int bad = 0;
    for (int i = t; i < 4096; i += 1024) {
      int e = (xu[i] >> 7) & 0xFF;
      if (e > 133 || (e > 0 && e < 90)) bad++;
    }
    for (int off = 32; off > 0; off >>= 1) bad += __shfl_down(bad, off, 64);
    if ((t & 63) == 0) tot[t >> 6] = bad;
    __syncthreads();
  }
  int sumb = 0;
#pragma unroll
  for (int i = 0; i < 16; i++) sumb += tot[i];
  int isf = (sumb > 200) ? 1 : 0;
  __syncthreads();

  if (blk < 16) {
    // ================= embsim =================
    bf16_t* nrm = (bf16_t*)shbuf;                   // 64 x 768, xor-swizzled
    int b = blk;
    // ---- phase 1: span max-pool + norm ----
    int e   = t >> 4;            // entity 0..63
    int l16 = t & 15;
    int d0  = l16 * 48;
    int st  = starts[b * NE_ + e];
    size_t off = ((size_t)(b * L_ + st)) * H_;
    float ss = 0.f;
    bf16x8 pv[6];
    if (isf) {
      const float* xp = (const float*)xv + off + d0;
#pragma unroll
      for (int c8 = 0; c8 < 6; c8++) {
        const float* p = xp + c8 * 8;
        bf16x8 o;
#pragma unroll
        for (int h = 0; h < 2; h++) {
          floatx4 r0 = *(const floatx4*)(p + h * 4);
          floatx4 r1 = *(const floatx4*)(p + H_ + h * 4);
          floatx4 r2 = *(const floatx4*)(p + 2 * H_ + h * 4);
          floatx4 r3 = *(const floatx4*)(p + 3 * H_ + h * 4);
#pragma unroll
          for (int q = 0; q < 4; q++) {
            float v = fmaxf(fmaxf(r0[q], r1[q]), fmaxf(r2[q], r3[q]));
            ss += v * v;
            o[h * 4 + q] = (bf16_t)v;
          }
        }
        pv[c8] = o;
      }
    } else {
      const bf16_t* xp = (const bf16_t*)xv + off + d0;
#pragma unroll
      for (int c8 = 0; c8 < 6; c8++) {
        const bf16_t* p = xp + c8 * 8;
        bf16x8 r0 = *(const bf16x8*)(p);
        bf16x8 r1 = *(const bf16x8*)(p + H_);
        bf16x8 r2 = *(const bf16x8*)(p + 2 * H_);
        bf16x8 r3 = *(const bf16x8*)(p + 3 * H_);
        bf16x8 o;
#pragma unroll
        for (int q = 0; q < 8; q++) {
          float v = fmaxf(fmaxf((float)r0[q], (float)r1[q]),
                          fmaxf((float)r2[q], (float)r3[q]));
          ss += v * v;
          o[q] = (bf16_t)v;
        }
        pv[c8] = o;
      }
    }
#pragma unroll
    for (int d = 1; d < 16; d <<= 1) ss += __shfl_xor(ss, d, 64);
    float inv = 1.0f / fmaxf(sqrtf(ss), 1e-8f);

    size_t gb = ((size_t)(b * 64 + e)) * 768 + d0;
    int rowbyte = e * 1536;
    int xw = (e & 7) << 4;
#pragma unroll
    for (int c8 = 0; c8 < 6; c8++) {
      *(bf16x8*)(embh + gb + c8 * 8) = pv[c8];
      bf16x8 o;
#pragma unroll
      for (int q = 0; q < 8; q++) o[q] = (bf16_t)((float)pv[c8][q] * inv);
      int byo = (rowbyte + (d0 + c8 * 8) * 2) ^ xw;
      *(bf16x8*)((char*)nrm + byo) = o;
    }
    __syncthreads();

    // ---- phase 2: cos tiles via MFMA (16 waves = 4x4 tiles) ----
    int w = t >> 6, lane = t & 63;
    int quad = lane >> 4, l15 = lane & 15;
    int ti = w >> 2, tj = w & 3;
    int rowA = ti * 16 + l15, rowB = tj * 16 + l15;
    int xa = (rowA & 7) << 4, xb = (rowB & 7) << 4;
    const char* nb = (const char*)nrm;
    floatx4 acc = {};
#pragma unroll 4
    for (int k0 = 0; k0 < 768; k0 += 32) {
      int cb = (k0 + quad * 8) * 2;
      bf16x8 aF = *(const bf16x8*)(nb + ((rowA * 1536 + cb) ^ xa));
      bf16x8 bF = *(const bf16x8*)(nb + ((rowB * 1536 + cb) ^ xb));
      acc = __builtin_amdgcn_mfma_f32_16x16x32_bf16(aF, bF, acc, 0, 0, 0);
    }

    // ---- phase 3: mean/var (ddof=1) + sim ----
    float s1 = acc[0] + acc[1] + acc[2] + acc[3];
    float s2 = acc[0] * acc[0] + acc[1] * acc[1] + acc[2] * acc[2] + acc[3] * acc[3];
#pragma unroll
    for (int d = 32; d > 0; d >>= 1) {
      s1 += __shfl_xor(s1, d, 64);
      s2 += __shfl_xor(s2, d, 64);
    }
    if (lane == 0) { red1[w] = s1; red2[w] = s2; }
    __syncthreads();
    if (t == 0) {
      float S1 = 0.f, S2 = 0.f;
#pragma unroll
      for (int i = 0; i < 16; i++) { S1 += red1[i]; S2 += red2[i]; }
      float mean = S1 * (1.0f / 4096.0f);
      float var = (S2 - 4096.0f * mean * mean) * (1.0f / 4095.0f);
      float sd = sqrtf(fmaxf(var, 0.f));
      scale_s = 1.0f / (sd + 1e-5f);
      thr_s = isf ? *(const float*)thr_ptr : (float)(*(const bf16_t*)thr_ptr);
    }
    __syncthreads();
    float sc = scale_s, th = thr_s;
    int ibase = ti * 16 + quad * 4;
    int j = tj * 16 + l15;
#pragma unroll
    for (int r = 0; r < 4; r++) {
      int i = ibase + r;
      if (j > i) {
        int p = i * 63 - (i * (i - 1)) / 2 + (j - i - 1);
        simv[b * NPAIR + p] = (acc[r] - th) * sc;
      }
    }
    return;
  }

  if (blk == 16) {
    // ================= canon + flag =================
    if (t == 0) flagout[0] = isf;
    for (int idx = t; idx < 2818; idx += 1024) {
      if (idx < 768)       canon[idx] = cvt_elem(w1, idx, isf);
      else if (idx < 1536) canon[idx] = cvt_elem(b1, idx - 768, isf);
      else if (idx < 2048) canon[idx] = cvt_elem(b2, idx - 1536, isf);
      else if (idx < 2304) canon[idx] = cvt_elem(b3, idx - 2048, isf);
      else if (idx < 2816) canon[idx] = cvt_elem(w4, idx - 2304, isf);
      else                 canon[idx] = cvt_elem(b4, idx - 2816, isf);
    }
    return;
  }

  // ================= 64x64 weight transpose =================
  int tix = blk - 17;
  const void* src; size_t srcoff; bf16_t* dst; int K, N;
  if (tix < 144)      { src = w1; srcoff = 768;               dst = w1abT;          K = 768; N = 768; }
  else if (tix < 288) { src = w1; srcoff = (size_t)769 * 768; dst = w1abT + 589824; K = 768; N = 768; tix -= 144; }
  else if (tix < 384) { src = w2; srcoff = 0;                 dst = w2T;            K = 768; N = 512; tix -= 288; }
  else                { src = w3; srcoff = 0;                 dst = w3T;            K = 512; N = 256; tix -= 384; }
  int tiles_k = K >> 6;
  int tn_t = tix / tiles_k, tk_t = tix - tn_t * tiles_k;
  bf16_t (*tile)[65] = (bf16_t(*)[65])shbuf;      // 64x65 bf16 = 8.3 KB
  int ty = t >> 6, tx = t & 63;
#pragma unroll
  for (int p = 0; p < 4; p++) {
    int kk = tk_t * 64 + p * 16 + ty;
    int nn = tn_t * 64 + tx;
    tile[p * 16 + ty][tx] = cvt_elem(src, srcoff + (size_t)kk * N + nn, isf);
  }
  __syncthreads();
#pragma unroll
  for (int p = 0; p < 4; p++) {
    int nn = tn_t * 64 + p * 16 + ty;
    int kk = tk_t * 64 + tx;
    dst[(size_t)nn * K + kk] = tile[tx][p * 16 + ty];
  }
}

// ---------------- K1: bf16 MFMA GEMM1, 64x128 tiles (192 blocks) ----------
__global__ __launch_bounds__(256) void gemm1_kernel(
    const bf16_t* __restrict__ A, const bf16_t* __restrict__ Bt,
    float* __restrict__ C) {
  const int K = 768, N = 1536;
  __shared__ __align__(16) bf16_t Asm[64 * 32];    // 4 KB
  __shared__ __align__(16) bf16_t Bsm[128 * 32];   // 8 KB
  int bm = blockIdx.x, bn = blockIdx.y;
  int t = threadIdx.x;
  int w = t >> 6, lane = t & 63;
  int quad = lane >> 4, l15 = lane & 15;
  int wm = w >> 1, wn = w & 1;                     // 2x2 waves, wave = 32x64

  floatx4 acc[2][4] = {};
  const char* Abase = (const char*)(A + (size_t)bm * 64 * K);
  const char* Bbase = (const char*)(Bt + (size_t)bn * 128 * K);
  const int rowbytes = K * 2;

  for (int k0 = 0; k0 < K; k0 += 32) {
    {   // A: 4 KB, wave-contiguous 1 KB regions (src pre-swizzled)
      int fo = w * 1024 + lane * 16;
      int row = fo >> 6, colb = fo & 63;
      __builtin_amdgcn_global_load_lds(
          (__attribute__((address_space(1))) char*)(Abase + (size_t)row * rowbytes + k0 * 2 + SWZ(colb, row)),
          (__attribute__((address_space(3))) char*)((char*)Asm + w * 1024),
          16, 0, 0);
    }
#pragma unroll
    for (int it = 0; it < 2; it++) {   // B: 8 KB (src pre-swizzled)
      int fo = (w * 2 + it) * 1024 + lane * 16;
      int row = fo >> 6, colb = fo & 63;
      __builtin_amdgcn_global_load_lds(
          (__attribute__((address_space(1))) char*)(Bbase + (size_t)row * rowbytes + k0 * 2 + SWZ(colb, row)),
          (__attribute__((address_space(3))) char*)((char*)Bsm + (w * 2 + it) * 1024),
          16, 0, 0);
    }
    __syncthreads();

    bf16x8 aF[2], bF[4];
#pragma unroll
    for (int tm = 0; tm < 2; tm++) {
      int ra = wm * 32 + tm * 16 + l15;
      aF[tm] = *((const bf16x8*)((const char*)Asm + ra * 64 + SWZ(quad * 16, ra)));
    }
#pragma unroll
    for (int tn = 0; tn < 4; tn++) {
      int rb = wn * 64 + tn * 16 + l15;
      bF[tn] = *((const bf16x8*)((const char*)Bsm + rb * 64 + SWZ(quad * 16, rb)));
    }
#pragma unroll
    for (int tm = 0; tm < 2; tm++)
#pragma unroll
      for (int tn = 0; tn < 4; tn++)
        acc[tm][tn] = __builtin_amdgcn_mfma_f32_16x16x32_bf16(aF[tm], bF[tn], acc[tm][tn], 0, 0, 0);
    __syncthreads();
  }

#pragma unroll
  for (int tm = 0; tm < 2; tm++) {
    int grow0 = bm * 64 + wm * 32 + tm * 16 + quad * 4;
#pragma unroll
    for (int tn = 0; tn < 4; tn++) {
      int gcol = bn * 128 + wn * 64 + tn * 16 + l15;
#pragma unroll
      for (int r = 0; r < 4; r++)
        C[(size_t)(grow0 + r) * N + gcol] = acc[tm][tn][r];
    }
  }
}

// ---------------- K2: GEMM2 fused, 512 thr / 8 waves, pipelined A --------
// tile 128 rows x 256 cols, grid (252,2). wave = 64x64 (wm=w>>2, wn=w&3).
// A rows padded to 40 elems (80 B) -> even bank spread for write+read.
// B staged with both-sides swizzle (T2). C1 for iter k+1 prefetched into
// regs before the barrier (overlaps B drain).
__global__ __launch_bounds__(512, 4) void gemm2_fused_kernel(
    const float* __restrict__ C1, const float* __restrict__ sim,
    const bf16_t* __restrict__ w2T, const bf16_t* __restrict__ canon,
    bf16_t* __restrict__ h2) {
  __shared__ __align__(16) bf16_t Asm[128 * 40];   // 10 KB, padded rows
  __shared__ __align__(16) bf16_t Bsm[256 * 32];   // 16 KB
  __shared__ int   rowI[128], rowJ[128];
  __shared__ float rowS[128];
  __shared__ bf16_t w1s[768], b1s[768];
  __shared__ float b2s[256];
  int bm = blockIdx.x, bn = blockIdx.y;
  int t = threadIdx.x;

  if (t < 128) {
    int r = bm * 128 + t;
    int b = r / NPAIR, p = r - b * NPAIR;
    int i = 0, rem = p;
    while (rem >= 63 - i) { rem -= 63 - i; i++; }
    rowI[t] = b * 64 + i;
    rowJ[t] = b * 64 + i + 1 + rem;
    rowS[t] = sim[r];
  }
  for (int c = t; c < 768; c += 512) { w1s[c] = canon[c]; b1s[c] = canon[768 + c]; }
  if (t < 256) b2s[t] = (float)canon[1536 + bn * 256 + t];
  __syncthreads();

  int w = t >> 6, lane = t & 63;
  int quad = lane >> 4, l15 = lane & 15;
  int wm = w >> 2, wn = w & 3;
  floatx4 acc[4][4] = {};

  const char* Bbase = (const char*)(w2T + (size_t)bn * 256 * 768);

  int arow = t >> 2;             // 0..127
  int acolc = (t & 3) * 8;       // 0,8,16,24
  const float* Ai = C1 + (size_t)rowI[arow] * 1536 + acolc;
  const float* Aj = C1 + (size_t)rowJ[arow] * 1536 + 768 + acolc;
  float s = rowS[arow];
  bf16_t* awr = Asm + arow * 40 + acolc;

  // initial prefetch (k0 = 0)
  float4 pi0 = *(const float4*)(Ai);
  float4 pi1 = *(const float4*)(Ai + 4);
  float4 pj0 = *(const float4*)(Aj);
  float4 pj1 = *(const float4*)(Aj + 4);

  for (int k0 = 0; k0 < 768; k0 += 32) {
    // B staging: 16 KB, wave-contiguous 2 KB regions (src pre-swizzled)
#pragma unroll
    for (int it = 0; it < 2; it++) {
      int fo = w * 2048 + it * 1024 + lane * 16;
      int row = fo >> 6, colb = fo & 63;
      __builtin_amdgcn_global_load_lds(
          (__attribute__((address_space(1))) char*)(Bbase + (size_t)row * 1536 + k0 * 2 + SWZ(colb, row)),
          (__attribute__((address_space(3))) char*)((char*)Bsm + w * 2048 + it * 1024),
          16, 0, 0);
    }
    // A: compute 8 bf16 from prefetched regs, one ds_write_b128
    {
      int kc = k0 + acolc;
      bf16x8 o;
      const bf16x8 wv8 = *(const bf16x8*)(w1s + kc);
      const bf16x8 bv8 = *(const bf16x8*)(b1s + kc);
      o[0] = (bf16_t)fmaxf(pi0.x + pj0.x + s * (float)wv8[0] + (float)bv8[0], 0.f);
      o[1] = (bf16_t)fmaxf(pi0.y + pj0.y + s * (float)wv8[1] + (float)bv8[1], 0.f);
      o[2] = (bf16_t)fmaxf(pi0.z + pj0.z + s * (float)wv8[2] + (float)bv8[2], 0.f);
      o[3] = (bf16_t)fmaxf(pi0.w + pj0.w + s * (float)wv8[3] + (float)bv8[3], 0.f);
      o[4] = (bf16_t)fmaxf(pi1.x + pj1.x + s * (float)wv8[4] + (float)bv8[4], 0.f);
      o[5] = (bf16_t)fmaxf(pi1.y + pj1.y + s * (float)wv8[5] + (float)bv8[5], 0.f);
      o[6] = (bf16_t)fmaxf(pi1.z + pj1.z + s * (float)wv8[6] + (float)bv8[6], 0.f);
      o[7] = (bf16_t)fmaxf(pi1.w + pj1.w + s * (float)wv8[7] + (float)bv8[7], 0.f);
      *(bf16x8*)awr = o;
    }
    // prefetch next iter's C1 (rides the same barrier drain as B staging)
    if (k0 + 32 < 768) {
      pi0 = *(const float4*)(Ai + k0 + 32);
      pi1 = *(const float4*)(Ai + k0 + 36);
      pj0 = *(const float4*)(Aj + k0 + 32);
      pj1 = *(const float4*)(Aj + k0 + 36);
    }
    __syncthreads();

    bf16x8 aF[4], bF[4];
#pragma unroll
    for (int tm = 0; tm < 4; tm++)
      aF[tm] = *((const bf16x8*)(Asm + (wm * 64 + tm * 16 + l15) * 40 + quad * 8));
#pragma unroll
    for (int tn = 0; tn < 4; tn++) {
      int rb = wn * 64 + tn * 16 + l15;
      bF[tn] = *((const bf16x8*)((const char*)Bsm + rb * 64 + SWZ(quad * 16, rb)));
    }
#pragma unroll
    for (int tm = 0; tm < 4; tm++)
#pragma unroll
      for (int tn = 0; tn < 4; tn++)
        acc[tm][tn] = __builtin_amdgcn_mfma_f32_16x16x32_bf16(aF[tm], bF[tn], acc[tm][tn], 0, 0, 0);
    __syncthreads();
  }

  // epilogue: bias + relu -> bf16 h2
#pragma unroll
  for (int tm = 0; tm < 4; tm++) {
    int grow0 = bm * 128 + wm * 64 + tm * 16 + quad * 4;
#pragma unroll
    for (int tn = 0; tn < 4; tn++) {
      int lcol = wn * 64 + tn * 16 + l15;
      int gcol = bn * 256 + lcol;
#pragma unroll
      for (int r = 0; r < 4; r++) {
        float v = fmaxf(acc[tm][tn][r] + b2s[lcol], 0.f);
        h2[(size_t)(grow0 + r) * 512 + gcol] = (bf16_t)v;
      }
    }
  }
}

// ---------------- K3: fused layer-3 GEMM + final, 64-row tiles ----------
// tile 64 rows x 256 cols (full N), grid 504. 4 waves, each 64x64 (wn=w).
__global__ __launch_bounds__(256) void gemm3_fused_kernel(
    const bf16_t* __restrict__ h2, const bf16_t* __restrict__ w3T,
    const bf16_t* __restrict__ canon, const int* __restrict__ flagp,
    void* __restrict__ out) {
  __shared__ __align__(16) bf16_t Asm[64 * 32];    // 4 KB
  __shared__ __align__(16) bf16_t Bsm[256 * 32];   // 16 KB
  __shared__ float part[64][2][4];                 // [row][c][wave]
  __shared__ float w4s[512];
  __shared__ float b3s[256];
  int bm = blockIdx.x;
  int t = threadIdx.x;
  int w = t >> 6, lane = t & 63;
  int quad = lane >> 4, l15 = lane & 15;

  w4s[t]       = (float)canon[2304 + t];
  w4s[256 + t] = (float)canon[2304 + 256 + t];
  b3s[t]       = (float)canon[2048 + t];

  floatx4 acc[4][4] = {};
  const char* Abase = (const char*)(h2 + (size_t)bm * 64 * 512);
  const char* Bbase = (const char*)w3T;

  for (int k0 = 0; k0 < 512; k0 += 32) {
    {   // A: 4 KB, wave-contiguous 1 KB regions (src pre-swizzled)
      int fo = w * 1024 + lane * 16;
      int row = fo >> 6, colb = fo & 63;
      __builtin_amdgcn_global_load_lds(
          (__attribute__((address_space(1))) char*)(Abase + (size_t)row * 1024 + k0 * 2 + SWZ(colb, row)),
          (__attribute__((address_space(3))) char*)((char*)Asm + w * 1024),
          16, 0, 0);
    }
#pragma unroll
    for (int it = 0; it < 4; it++) {   // B: 16 KB (src pre-swizzled)
      int fo = w * 4096 + it * 1024 + lane * 16;
      int row = fo >> 6, colb = fo & 63;
      __builtin_amdgcn_global_load_lds(
          (__attribute__((address_space(1))) char*)(Bbase + (size_t)row * 1024 + k0 * 2 + SWZ(colb, row)),
          (__attribute__((address_space(3))) char*)((char*)Bsm + w * 4096 + it * 1024),
          16, 0, 0);
    }
    __syncthreads();

    bf16x8 aF[4], bF[4];
#pragma unroll
    for (int tm = 0; tm < 4; tm++) {
      int ra = tm * 16 + l15;
      aF[tm] = *((const bf16x8*)((const char*)Asm + ra * 64 + SWZ(quad * 16, ra)));
    }
#pragma unroll
    for (int tn = 0; tn < 4; tn++) {
      int rb = w * 64 + tn * 16 + l15;
      bF[tn] = *((const bf16x8*)((const char*)Bsm + rb * 64 + SWZ(quad * 16, rb)));
    }
#pragma unroll
    for (int tm = 0; tm < 4; tm++)
#pragma unroll
      for (int tn = 0; tn < 4; tn++)
        acc[tm][tn] = __builtin_amdgcn_mfma_f32_16x16x32_bf16(aF[tm], bF[tn], acc[tm][tn], 0, 0, 0);
    __syncthreads();
  }

#pragma unroll
  for (int tm = 0; tm < 4; tm++) {
#pragma unroll
    for (int reg = 0; reg < 4; reg++) {
      float p0 = 0.f, p1 = 0.f;
#pragma unroll
      for (int tn = 0; tn < 4; tn++) {
        int col = w * 64 + tn * 16 + l15;
        float v = fmaxf(acc[tm][tn][reg] + b3s[col], 0.f);
        p0 += v * w4s[col * 2];
        p1 += v * w4s[col * 2 + 1];
      }
#pragma unroll
      for (int d = 1; d < 16; d <<= 1) {
        p0 += __shfl_xor(p0, d, 64);
        p1 += __shfl_xor(p1, d, 64);
      }
      if (l15 == 0) {
        int r = tm * 16 + quad * 4 + reg;
        part[r][0][w] = p0;
        part[r][1][w] = p1;
      }
    }
  }
  __syncthreads();
  if (t < 128) {
    int r = t >> 1, c = t & 1;
    float v = part[r][c][0] + part[r][c][1] + part[r][c][2] + part[r][c][3]
            + (float)canon[2816 + c];
    size_t rg = (size_t)bm * 64 + r;
    if (flagp[0]) ((float*)out)[rg * 2 + c] = v;
    else          ((bf16_t*)out)[rg * 2 + c] = (bf16_t)v;
  }
}

// ---------------- launch ----------------
extern "C" void kernel_launch(void* const* d_in, const int* in_sizes, int n_in,
                              void* d_out, int out_size, void* d_ws, size_t ws_size,
                              hipStream_t stream) {
  const void* x      = d_in[0];
  const void* thr    = d_in[1];
  const void* w1     = d_in[2];
  const void* b1     = d_in[3];
  const void* w2     = d_in[4];
  const void* b2     = d_in[5];
  const void* w3     = d_in[6];
  const void* b3     = d_in[7];
  const void* w4     = d_in[8];
  const void* b4     = d_in[9];
  const int*  starts = (const int*)d_in[10];

  char* ws = (char*)d_ws;
  bf16_t* embh  = (bf16_t*)(ws + OFF_EMBH);
  float*  simv  = (float*)(ws + OFF_SIM);
  bf16_t* w1abT = (bf16_t*)(ws + OFF_W1ABT);
  bf16_t* w2T   = (bf16_t*)(ws + OFF_W2T);
  bf16_t* w3T   = (bf16_t*)(ws + OFF_W3T);
  float*  C1    = (float*)(ws + OFF_C1);
  bf16_t* h2    = (bf16_t*)(ws + OFF_H2);
  int*    flag  = (int*)(ws + OFF_FLAG);
  bf16_t* canon = (bf16_t*)(ws + OFF_CANON);

  // merged: flag + canon + transposes + (span max-pool / cosine / std / sim)
  prep_embsim_kernel<<<433, 1024, 0, stream>>>(
      (const unsigned short*)x, x, starts, thr,
      w1, w2, w3, b1, b2, b3, w4, b4,
      flag, w1abT, w2T, w3T, canon, embh, simv);

  // C1 = emb @ [W1a | W1b] : [1024,768] x [768,1536] -> fp32
  {
    dim3 g(1024 / 64, 1536 / 128);
    gemm1_kernel<<<g, 256, 0, stream>>>(embh, w1abT, C1);
  }

  // h2 = relu(h1 @ w2 + b2), h1 assembled on the fly (pipelined)
  {
    dim3 g(NROWS / 128, 2);
    gemm2_fused_kernel<<<g, 512, 0, stream>>>(C1, simv, w2T, canon, h2);
  }

  // h3 = relu(h2 @ w3 + b3); logits = h3 @ w4 + b4
  gemm3_fused_kernel<<<NROWS / 64, 256, 0, stream>>>(h2, w3T, canon, flag, d_out);
}

// Round 6
// 263.937 us; speedup vs baseline: 1.1564x; 1.0208x over previous
//
#include <hip/hip_runtime.h>
#include <cstdint>
#include <cstddef>

// ---------------- problem constants ----------------
#define B_    16
#define L_    2048
#define H_    768
#define NE_   64
#define SPAN_ 4
#define NPAIR 2016              // 64*63/2
#define NROWS (B_ * NPAIR)      // 32256 = 252 * 128

typedef __bf16 bf16_t;
typedef __bf16 bf16x8 __attribute__((ext_vector_type(8)));
typedef __bf16 bf16x4 __attribute__((ext_vector_type(4)));
typedef float  floatx4 __attribute__((ext_vector_type(4)));

#define AS1 __attribute__((address_space(1)))
#define AS3 __attribute__((address_space(3)))

// ---------------- ws layout (bytes, all 256-aligned) ----------------
#define OFF_EMBH   ((size_t)3145728)
#define OFF_SIM    ((size_t)8126464)
#define OFF_W1ABT  ((size_t)8255488)
#define OFF_W2T    ((size_t)10614784)
#define OFF_W3T    ((size_t)11401216)
#define OFF_C1     ((size_t)11663360)
#define OFF_H2     ((size_t)67500032)
#define OFF_FLAG   ((size_t)117045248)
#define OFF_CANON  ((size_t)117045504)
// canon bf16: [0:768) w1row0, [768:1536) b1, [1536:2048) b2,
//             [2048:2304) b3, [2304:2816) w4, [2816:2818) b4

// T2 both-sides swizzle (rule #21): applied to the GLOBAL source byte-in-row
// and identically on the ds_read side (LDS dest stays linear).
#define SWZ(colb, row) ((colb) ^ (((row) & 3) << 4))

__device__ inline bf16_t cvt_elem(const void* p, size_t i, int isf) {
  if (isf) return (bf16_t)(((const float*)p)[i]);
  return ((const bf16_t*)p)[i];
}

// ---------------- K0 (merged): flag + canon + weight transposes + embsim ----
// grid 256 x 1024 threads (exactly one scheduling wave at 1 blk/CU).
//   blocks 0..15   : fused span max-pool + norm + MFMA cosine + std + sim
//   blocks 16..255 : block-stride over 417 units (u0 = canon, u1.. = 64x64
//                    LDS-tiled weight transposes of w1a/w1b/w2/w3)
__global__ __launch_bounds__(1024) void prep_embsim_kernel(
    const unsigned short* __restrict__ xu,          // == x, for flag scan
    const void* __restrict__ xv, const int* __restrict__ starts,
    const void* __restrict__ thr_ptr,
    const void* __restrict__ w1, const void* __restrict__ w2,
    const void* __restrict__ w3, const void* __restrict__ b1,
    const void* __restrict__ b2, const void* __restrict__ b3,
    const void* __restrict__ w4, const void* __restrict__ b4,
    int* __restrict__ flagout,
    bf16_t* __restrict__ w1abT, bf16_t* __restrict__ w2T,
    bf16_t* __restrict__ w3T, bf16_t* __restrict__ canon,
    bf16_t* __restrict__ embh, float* __restrict__ simv) {
  __shared__ __align__(16) char shbuf[98304];       // 96 KB: nrm / tile union
  __shared__ int   tot[16];
  __shared__ float red1[16], red2[16];
  __shared__ float scale_s, thr_s;

  int blk = blockIdx.x;
  int t = threadIdx.x;

  // ---- inline dtype flag (uniform across all blocks) ----
  {
    int bad = 0;
    for (int i = t; i < 4096; i += 1024) {
      int e = (xu[i] >> 7) & 0xFF;
      if (e > 133 || (e > 0 && e < 90)) bad++;
    }
    for (int off = 32; off > 0; off >>= 1) bad += __shfl_down(bad, off, 64);
    if ((t & 63) == 0) tot[t >> 6] = bad;
    __syncthreads();
  }
  int sumb = 0;
#pragma unroll
  for (int i = 0; i < 16; i++) sumb += tot[i];
  int isf = (sumb > 200) ? 1 : 0;
  __syncthreads();

  if (blk < 16) {
    // ================= embsim =================
    bf16_t* nrm = (bf16_t*)shbuf;                   // 64 x 768, xor-swizzled
    int b = blk;
    // ---- phase 1: span max-pool + norm ----
    int e   = t >> 4;            // entity 0..63
    int l16 = t & 15;
    int d0  = l16 * 48;
    int st  = starts[b * NE_ + e];
    size_t off = ((size_t)(b * L_ + st)) * H_;
    float ss = 0.f;
    bf16x8 pv[6];
    if (isf) {
      const float* xp = (const float*)xv + off + d0;
#pragma unroll
      for (int c8 = 0; c8 < 6; c8++) {
        const float* p = xp + c8 * 8;
        bf16x8 o;
#pragma unroll
        for (int h = 0; h < 2; h++) {
          floatx4 r0 = *(const floatx4*)(p + h * 4);
          floatx4 r1 = *(const floatx4*)(p + H_ + h * 4);
          floatx4 r2 = *(const floatx4*)(p + 2 * H_ + h * 4);
          floatx4 r3 = *(const floatx4*)(p + 3 * H_ + h * 4);
#pragma unroll
          for (int q = 0; q < 4; q++) {
            float v = fmaxf(fmaxf(r0[q], r1[q]), fmaxf(r2[q], r3[q]));
            ss += v * v;
            o[h * 4 + q] = (bf16_t)v;
          }
        }
        pv[c8] = o;
      }
    } else {
      const bf16_t* xp = (const bf16_t*)xv + off + d0;
#pragma unroll
      for (int c8 = 0; c8 < 6; c8++) {
        const bf16_t* p = xp + c8 * 8;
        bf16x8 r0 = *(const bf16x8*)(p);
        bf16x8 r1 = *(const bf16x8*)(p + H_);
        bf16x8 r2 = *(const bf16x8*)(p + 2 * H_);
        bf16x8 r3 = *(const bf16x8*)(p + 3 * H_);
        bf16x8 o;
#pragma unroll
        for (int q = 0; q < 8; q++) {
          float v = fmaxf(fmaxf((float)r0[q], (float)r1[q]),
                          fmaxf((float)r2[q], (float)r3[q]));
          ss += v * v;
          o[q] = (bf16_t)v;
        }
        pv[c8] = o;
      }
    }
#pragma unroll
    for (int d = 1; d < 16; d <<= 1) ss += __shfl_xor(ss, d, 64);
    float inv = 1.0f / fmaxf(sqrtf(ss), 1e-8f);

    size_t gb = ((size_t)(b * 64 + e)) * 768 + d0;
    int rowbyte = e * 1536;
    int xw = (e & 7) << 4;
#pragma unroll
    for (int c8 = 0; c8 < 6; c8++) {
      *(bf16x8*)(embh + gb + c8 * 8) = pv[c8];
      bf16x8 o;
#pragma unroll
      for (int q = 0; q < 8; q++) o[q] = (bf16_t)((float)pv[c8][q] * inv);
      int byo = (rowbyte + (d0 + c8 * 8) * 2) ^ xw;
      *(bf16x8*)((char*)nrm + byo) = o;
    }
    __syncthreads();

    // ---- phase 2: cos tiles via MFMA (16 waves = 4x4 tiles) ----
    int w = t >> 6, lane = t & 63;
    int quad = lane >> 4, l15 = lane & 15;
    int ti = w >> 2, tj = w & 3;
    int rowA = ti * 16 + l15, rowB = tj * 16 + l15;
    int xa = (rowA & 7) << 4, xb = (rowB & 7) << 4;
    const char* nb = (const char*)nrm;
    floatx4 acc = {};
#pragma unroll 4
    for (int k0 = 0; k0 < 768; k0 += 32) {
      int cb = (k0 + quad * 8) * 2;
      bf16x8 aF = *(const bf16x8*)(nb + ((rowA * 1536 + cb) ^ xa));
      bf16x8 bF = *(const bf16x8*)(nb + ((rowB * 1536 + cb) ^ xb));
      acc = __builtin_amdgcn_mfma_f32_16x16x32_bf16(aF, bF, acc, 0, 0, 0);
    }

    // ---- phase 3: mean/var (ddof=1) + sim ----
    float s1 = acc[0] + acc[1] + acc[2] + acc[3];
    float s2 = acc[0] * acc[0] + acc[1] * acc[1] + acc[2] * acc[2] + acc[3] * acc[3];
#pragma unroll
    for (int d = 32; d > 0; d >>= 1) {
      s1 += __shfl_xor(s1, d, 64);
      s2 += __shfl_xor(s2, d, 64);
    }
    if (lane == 0) { red1[w] = s1; red2[w] = s2; }
    __syncthreads();
    if (t == 0) {
      float S1 = 0.f, S2 = 0.f;
#pragma unroll
      for (int i = 0; i < 16; i++) { S1 += red1[i]; S2 += red2[i]; }
      float mean = S1 * (1.0f / 4096.0f);
      float var = (S2 - 4096.0f * mean * mean) * (1.0f / 4095.0f);
      float sd = sqrtf(fmaxf(var, 0.f));
      scale_s = 1.0f / (sd + 1e-5f);
      thr_s = isf ? *(const float*)thr_ptr : (float)(*(const bf16_t*)thr_ptr);
    }
    __syncthreads();
    float sc = scale_s, th = thr_s;
    int ibase = ti * 16 + quad * 4;
    int j = tj * 16 + l15;
#pragma unroll
    for (int r = 0; r < 4; r++) {
      int i = ibase + r;
      if (j > i) {
        int p = i * 63 - (i * (i - 1)) / 2 + (j - i - 1);
        simv[b * NPAIR + p] = (acc[r] - th) * sc;
      }
    }
    return;
  }

  // ================= blocks 16..255: canon + transposes (block-stride) ====
  for (int u = blk - 16; u < 417; u += 240) {
    if (u == 0) {
      if (t == 0) flagout[0] = isf;
      for (int idx = t; idx < 2818; idx += 1024) {
        if (idx < 768)       canon[idx] = cvt_elem(w1, idx, isf);
        else if (idx < 1536) canon[idx] = cvt_elem(b1, idx - 768, isf);
        else if (idx < 2048) canon[idx] = cvt_elem(b2, idx - 1536, isf);
        else if (idx < 2304) canon[idx] = cvt_elem(b3, idx - 2048, isf);
        else if (idx < 2816) canon[idx] = cvt_elem(w4, idx - 2304, isf);
        else                 canon[idx] = cvt_elem(b4, idx - 2816, isf);
      }
    } else {
      int tix = u - 1;
      const void* src; size_t srcoff; bf16_t* dst; int K, N;
      if (tix < 144)      { src = w1; srcoff = 768;               dst = w1abT;          K = 768; N = 768; }
      else if (tix < 288) { src = w1; srcoff = (size_t)769 * 768; dst = w1abT + 589824; K = 768; N = 768; tix -= 144; }
      else if (tix < 384) { src = w2; srcoff = 0;                 dst = w2T;            K = 768; N = 512; tix -= 288; }
      else                { src = w3; srcoff = 0;                 dst = w3T;            K = 512; N = 256; tix -= 384; }
      int tiles_k = K >> 6;
      int tn_t = tix / tiles_k, tk_t = tix - tn_t * tiles_k;
      bf16_t (*tile)[65] = (bf16_t(*)[65])shbuf;      // 64x65 bf16 = 8.3 KB
      int ty = t >> 6, tx = t & 63;
      __syncthreads();          // protect tile buffer across stride iterations
#pragma unroll
      for (int p = 0; p < 4; p++) {
        int kk = tk_t * 64 + p * 16 + ty;
        int nn = tn_t * 64 + tx;
        tile[p * 16 + ty][tx] = cvt_elem(src, srcoff + (size_t)kk * N + nn, isf);
      }
      __syncthreads();
#pragma unroll
      for (int p = 0; p < 4; p++) {
        int nn = tn_t * 64 + p * 16 + ty;
        int kk = tk_t * 64 + tx;
        dst[(size_t)nn * K + kk] = tile[tx][p * 16 + ty];
      }
    }
  }
}

// ---------------- K1: bf16 MFMA GEMM1, 64x128 tiles (192 blocks) ----------
__global__ __launch_bounds__(256) void gemm1_kernel(
    const bf16_t* __restrict__ A, const bf16_t* __restrict__ Bt,
    float* __restrict__ C) {
  const int K = 768, N = 1536;
  __shared__ __align__(16) bf16_t Asm[64 * 32];    // 4 KB
  __shared__ __align__(16) bf16_t Bsm[128 * 32];   // 8 KB
  int bm = blockIdx.x, bn = blockIdx.y;
  int t = threadIdx.x;
  int w = t >> 6, lane = t & 63;
  int quad = lane >> 4, l15 = lane & 15;
  int wm = w >> 1, wn = w & 1;                     // 2x2 waves, wave = 32x64

  floatx4 acc[2][4] = {};
  const char* Abase = (const char*)(A + (size_t)bm * 64 * K);
  const char* Bbase = (const char*)(Bt + (size_t)bn * 128 * K);
  const int rowbytes = K * 2;

  for (int k0 = 0; k0 < K; k0 += 32) {
    {   // A: 4 KB, wave-contiguous 1 KB regions (src pre-swizzled)
      int fo = w * 1024 + lane * 16;
      int row = fo >> 6, colb = fo & 63;
      __builtin_amdgcn_global_load_lds(
          (AS1 char*)(Abase + (size_t)row * rowbytes + k0 * 2 + SWZ(colb, row)),
          (AS3 char*)((char*)Asm + w * 1024),
          16, 0, 0);
    }
#pragma unroll
    for (int it = 0; it < 2; it++) {   // B: 8 KB (src pre-swizzled)
      int fo = (w * 2 + it) * 1024 + lane * 16;
      int row = fo >> 6, colb = fo & 63;
      __builtin_amdgcn_global_load_lds(
          (AS1 char*)(Bbase + (size_t)row * rowbytes + k0 * 2 + SWZ(colb, row)),
          (AS3 char*)((char*)Bsm + (w * 2 + it) * 1024),
          16, 0, 0);
    }
    __syncthreads();

    bf16x8 aF[2], bF[4];
#pragma unroll
    for (int tm = 0; tm < 2; tm++) {
      int ra = wm * 32 + tm * 16 + l15;
      aF[tm] = *((const bf16x8*)((const char*)Asm + ra * 64 + SWZ(quad * 16, ra)));
    }
#pragma unroll
    for (int tn = 0; tn < 4; tn++) {
      int rb = wn * 64 + tn * 16 + l15;
      bF[tn] = *((const bf16x8*)((const char*)Bsm + rb * 64 + SWZ(quad * 16, rb)));
    }
#pragma unroll
    for (int tm = 0; tm < 2; tm++)
#pragma unroll
      for (int tn = 0; tn < 4; tn++)
        acc[tm][tn] = __builtin_amdgcn_mfma_f32_16x16x32_bf16(aF[tm], bF[tn], acc[tm][tn], 0, 0, 0);
    __syncthreads();
  }

#pragma unroll
  for (int tm = 0; tm < 2; tm++) {
    int grow0 = bm * 64 + wm * 32 + tm * 16 + quad * 4;
#pragma unroll
    for (int tn = 0; tn < 4; tn++) {
      int gcol = bn * 128 + wn * 64 + tn * 16 + l15;
#pragma unroll
      for (int r = 0; r < 4; r++)
        C[(size_t)(grow0 + r) * N + gcol] = acc[tm][tn][r];
    }
  }
}

// ---------------- K2: GEMM2 fused, T3-minimum double-buffered pipeline ----
// tile 128 x 256, grid (252,2), 512 thr / 8 waves (64x64 each).
// Per K-step: issue next B-stage (global_load_lds) + ds_write next A BEFORE
// the current MFMA block; ONE barrier per step (loads drain under MFMA).
__global__ __launch_bounds__(512, 4) void gemm2_fused_kernel(
    const float* __restrict__ C1, const float* __restrict__ sim,
    const bf16_t* __restrict__ w2T, const bf16_t* __restrict__ canon,
    bf16_t* __restrict__ h2) {
  __shared__ __align__(16) bf16_t Asm[2][128 * 40];  // 2 x 10 KB, padded rows
  __shared__ __align__(16) bf16_t Bsm[2][256 * 32];  // 2 x 16 KB
  __shared__ int   rowI[128], rowJ[128];
  __shared__ float rowS[128];
  __shared__ bf16_t w1s[768], b1s[768];
  __shared__ float b2s[256];
  int bm = blockIdx.x, bn = blockIdx.y;
  int t = threadIdx.x;

  if (t < 128) {
    int r = bm * 128 + t;
    int b = r / NPAIR, p = r - b * NPAIR;
    int i = 0, rem = p;
    while (rem >= 63 - i) { rem -= 63 - i; i++; }
    rowI[t] = b * 64 + i;
    rowJ[t] = b * 64 + i + 1 + rem;
    rowS[t] = sim[r];
  }
  for (int c = t; c < 768; c += 512) { w1s[c] = canon[c]; b1s[c] = canon[768 + c]; }
  if (t < 256) b2s[t] = (float)canon[1536 + bn * 256 + t];
  __syncthreads();

  int w = t >> 6, lane = t & 63;
  int quad = lane >> 4, l15 = lane & 15;
  int wm = w >> 2, wn = w & 3;
  floatx4 acc[4][4] = {};

  const char* Bbase = (const char*)(w2T + (size_t)bn * 256 * 768);

  int arow = t >> 2;             // 0..127
  int acolc = (t & 3) * 8;       // 0,8,16,24
  const float* Ai = C1 + (size_t)rowI[arow] * 1536 + acolc;
  const float* Aj = C1 + (size_t)rowJ[arow] * 1536 + 768 + acolc;
  float s = rowS[arow];

  // ---- prologue: stage k-step 0 into buffer 0 ----
  float4 pi0 = *(const float4*)(Ai);
  float4 pi1 = *(const float4*)(Ai + 4);
  float4 pj0 = *(const float4*)(Aj);
  float4 pj1 = *(const float4*)(Aj + 4);
#pragma unroll
  for (int it = 0; it < 2; it++) {
    int fo = w * 2048 + it * 1024 + lane * 16;
    int row = fo >> 6, colb = fo & 63;
    __builtin_amdgcn_global_load_lds(
        (AS1 char*)(Bbase + (size_t)row * 1536 + SWZ(colb, row)),
        (AS3 char*)((char*)&Bsm[0][0] + w * 2048 + it * 1024),
        16, 0, 0);
  }
  {
    int kc = acolc;
    bf16x8 o;
    const bf16x8 wv8 = *(const bf16x8*)(w1s + kc);
    const bf16x8 bv8 = *(const bf16x8*)(b1s + kc);
    o[0] = (bf16_t)fmaxf(pi0.x + pj0.x + s * (float)wv8[0] + (float)bv8[0], 0.f);
    o[1] = (bf16_t)fmaxf(pi0.y + pj0.y + s * (float)wv8[1] + (float)bv8[1], 0.f);
    o[2] = (bf16_t)fmaxf(pi0.z + pj0.z + s * (float)wv8[2] + (float)bv8[2], 0.f);
    o[3] = (bf16_t)fmaxf(pi0.w + pj0.w + s * (float)wv8[3] + (float)bv8[3], 0.f);
    o[4] = (bf16_t)fmaxf(pi1.x + pj1.x + s * (float)wv8[4] + (float)bv8[4], 0.f);
    o[5] = (bf16_t)fmaxf(pi1.y + pj1.y + s * (float)wv8[5] + (float)bv8[5], 0.f);
    o[6] = (bf16_t)fmaxf(pi1.z + pj1.z + s * (float)wv8[6] + (float)bv8[6], 0.f);
    o[7] = (bf16_t)fmaxf(pi1.w + pj1.w + s * (float)wv8[7] + (float)bv8[7], 0.f);
    *(bf16x8*)(&Asm[0][arow * 40 + acolc]) = o;
  }
  // prefetch C1 regs for k-step 1
  pi0 = *(const float4*)(Ai + 32);
  pi1 = *(const float4*)(Ai + 36);
  pj0 = *(const float4*)(Aj + 32);
  pj1 = *(const float4*)(Aj + 36);
  __syncthreads();

  // ---- main loop: 24 K-steps, one barrier each ----
  for (int kt = 0; kt < 24; ++kt) {
    int cur = kt & 1, nxt = cur ^ 1;
    if (kt < 23) {
      int k1 = (kt + 1) * 32;
#pragma unroll
      for (int it = 0; it < 2; it++) {   // stage next B
        int fo = w * 2048 + it * 1024 + lane * 16;
        int row = fo >> 6, colb = fo & 63;
        __builtin_amdgcn_global_load_lds(
            (AS1 char*)(Bbase + (size_t)row * 1536 + k1 * 2 + SWZ(colb, row)),
            (AS3 char*)((char*)&Bsm[nxt][0] + w * 2048 + it * 1024),
            16, 0, 0);
      }
      {  // assemble + ds_write next A (uses regs prefetched last iter)
        int kc = k1 + acolc;
        bf16x8 o;
        const bf16x8 wv8 = *(const bf16x8*)(w1s + kc);
        const bf16x8 bv8 = *(const bf16x8*)(b1s + kc);
        o[0] = (bf16_t)fmaxf(pi0.x + pj0.x + s * (float)wv8[0] + (float)bv8[0], 0.f);
        o[1] = (bf16_t)fmaxf(pi0.y + pj0.y + s * (float)wv8[1] + (float)bv8[1], 0.f);
        o[2] = (bf16_t)fmaxf(pi0.z + pj0.z + s * (float)wv8[2] + (float)bv8[2], 0.f);
        o[3] = (bf16_t)fmaxf(pi0.w + pj0.w + s * (float)wv8[3] + (float)bv8[3], 0.f);
        o[4] = (bf16_t)fmaxf(pi1.x + pj1.x + s * (float)wv8[4] + (float)bv8[4], 0.f);
        o[5] = (bf16_t)fmaxf(pi1.y + pj1.y + s * (float)wv8[5] + (float)bv8[5], 0.f);
        o[6] = (bf16_t)fmaxf(pi1.z + pj1.z + s * (float)wv8[6] + (float)bv8[6], 0.f);
        o[7] = (bf16_t)fmaxf(pi1.w + pj1.w + s * (float)wv8[7] + (float)bv8[7], 0.f);
        *(bf16x8*)(&Asm[nxt][arow * 40 + acolc]) = o;
      }
      if (kt < 22) {   // prefetch C1 regs for k-step kt+2
        int k2 = (kt + 2) * 32;
        pi0 = *(const float4*)(Ai + k2);
        pi1 = *(const float4*)(Ai + k2 + 4);
        pj0 = *(const float4*)(Aj + k2);
        pj1 = *(const float4*)(Aj + k2 + 4);
      }
    }

    bf16x8 aF[4], bF[4];
#pragma unroll
    for (int tm = 0; tm < 4; tm++)
      aF[tm] = *((const bf16x8*)(&Asm[cur][(wm * 64 + tm * 16 + l15) * 40 + quad * 8]));
#pragma unroll
    for (int tn = 0; tn < 4; tn++) {
      int rb = wn * 64 + tn * 16 + l15;
      bF[tn] = *((const bf16x8*)((const char*)&Bsm[cur][0] + rb * 64 + SWZ(quad * 16, rb)));
    }
#pragma unroll
    for (int tm = 0; tm < 4; tm++)
#pragma unroll
      for (int tn = 0; tn < 4; tn++)
        acc[tm][tn] = __builtin_amdgcn_mfma_f32_16x16x32_bf16(aF[tm], bF[tn], acc[tm][tn], 0, 0, 0);
    __syncthreads();   // drains next-step loads/writes; protects cur for reuse
  }

  // epilogue: bias + relu -> bf16 h2
#pragma unroll
  for (int tm = 0; tm < 4; tm++) {
    int grow0 = bm * 128 + wm * 64 + tm * 16 + quad * 4;
#pragma unroll
    for (int tn = 0; tn < 4; tn++) {
      int lcol = wn * 64 + tn * 16 + l15;
      int gcol = bn * 256 + lcol;
#pragma unroll
      for (int r = 0; r < 4; r++) {
        float v = fmaxf(acc[tm][tn][r] + b2s[lcol], 0.f);
        h2[(size_t)(grow0 + r) * 512 + gcol] = (bf16_t)v;
      }
    }
  }
}

// ---------------- K3: GEMM3 fused, T3-minimum double-buffered pipeline ----
// tile 64 x 256 (full N), grid 504, 4 waves (64x64 each, wn=w).
__global__ __launch_bounds__(256) void gemm3_fused_kernel(
    const bf16_t* __restrict__ h2, const bf16_t* __restrict__ w3T,
    const bf16_t* __restrict__ canon, const int* __restrict__ flagp,
    void* __restrict__ out) {
  __shared__ __align__(16) bf16_t Asm[2][64 * 32];   // 2 x 4 KB
  __shared__ __align__(16) bf16_t Bsm[2][256 * 32];  // 2 x 16 KB
  __shared__ float part[64][2][4];                 // [row][c][wave]
  __shared__ float w4s[512];
  __shared__ float b3s[256];
  int bm = blockIdx.x;
  int t = threadIdx.x;
  int w = t >> 6, lane = t & 63;
  int quad = lane >> 4, l15 = lane & 15;

  w4s[t]       = (float)canon[2304 + t];
  w4s[256 + t] = (float)canon[2304 + 256 + t];
  b3s[t]       = (float)canon[2048 + t];

  floatx4 acc[4][4] = {};
  const char* Abase = (const char*)(h2 + (size_t)bm * 64 * 512);
  const char* Bbase = (const char*)w3T;

  // ---- prologue: stage k-step 0 into buffer 0 ----
  {
    int fo = w * 1024 + lane * 16;
    int row = fo >> 6, colb = fo & 63;
    __builtin_amdgcn_global_load_lds(
        (AS1 char*)(Abase + (size_t)row * 1024 + SWZ(colb, row)),
        (AS3 char*)((char*)&Asm[0][0] + w * 1024),
        16, 0, 0);
  }
#pragma unroll
  for (int it = 0; it < 4; it++) {
    int fo = w * 4096 + it * 1024 + lane * 16;
    int row = fo >> 6, colb = fo & 63;
    __builtin_amdgcn_global_load_lds(
        (AS1 char*)(Bbase + (size_t)row * 1024 + SWZ(colb, row)),
        (AS3 char*)((char*)&Bsm[0][0] + w * 4096 + it * 1024),
        16, 0, 0);
  }
  __syncthreads();

  // ---- main loop: 16 K-steps, one barrier each ----
  for (int kt = 0; kt < 16; ++kt) {
    int cur = kt & 1, nxt = cur ^ 1;
    if (kt < 15) {
      int k1 = (kt + 1) * 32;
      {   // stage next A
        int fo = w * 1024 + lane * 16;
        int row = fo >> 6, colb = fo & 63;
        __builtin_amdgcn_global_load_lds(
            (AS1 char*)(Abase + (size_t)row * 1024 + k1 * 2 + SWZ(colb, row)),
            (AS3 char*)((char*)&Asm[nxt][0] + w * 1024),
            16, 0, 0);
      }
#pragma unroll
      for (int it = 0; it < 4; it++) {   // stage next B
        int fo = w * 4096 + it * 1024 + lane * 16;
        int row = fo >> 6, colb = fo & 63;
        __builtin_amdgcn_global_load_lds(
            (AS1 char*)(Bbase + (size_t)row * 1024 + k1 * 2 + SWZ(colb, row)),
            (AS3 char*)((char*)&Bsm[nxt][0] + w * 4096 + it * 1024),
            16, 0, 0);
      }
    }

    bf16x8 aF[4], bF[4];
#pragma unroll
    for (int tm = 0; tm < 4; tm++) {
      int ra = tm * 16 + l15;
      aF[tm] = *((const bf16x8*)((const char*)&Asm[cur][0] + ra * 64 + SWZ(quad * 16, ra)));
    }
#pragma unroll
    for (int tn = 0; tn < 4; tn++) {
      int rb = w * 64 + tn * 16 + l15;
      bF[tn] = *((const bf16x8*)((const char*)&Bsm[cur][0] + rb * 64 + SWZ(quad * 16, rb)));
    }
#pragma unroll
    for (int tm = 0; tm < 4; tm++)
#pragma unroll
      for (int tn = 0; tn < 4; tn++)
        acc[tm][tn] = __builtin_amdgcn_mfma_f32_16x16x32_bf16(aF[tm], bF[tn], acc[tm][tn], 0, 0, 0);
    __syncthreads();
  }

#pragma unroll
  for (int tm = 0; tm < 4; tm++) {
#pragma unroll
    for (int reg = 0; reg < 4; reg++) {
      float p0 = 0.f, p1 = 0.f;
#pragma unroll
      for (int tn = 0; tn < 4; tn++) {
        int col = w * 64 + tn * 16 + l15;
        float v = fmaxf(acc[tm][tn][reg] + b3s[col], 0.f);
        p0 += v * w4s[col * 2];
        p1 += v * w4s[col * 2 + 1];
      }
#pragma unroll
      for (int d = 1; d < 16; d <<= 1) {
        p0 += __shfl_xor(p0, d, 64);
        p1 += __shfl_xor(p1, d, 64);
      }
      if (l15 == 0) {
        int r = tm * 16 + quad * 4 + reg;
        part[r][0][w] = p0;
        part[r][1][w] = p1;
      }
    }
  }
  __syncthreads();
  if (t < 128) {
    int r = t >> 1, c = t & 1;
    float v = part[r][c][0] + part[r][c][1] + part[r][c][2] + part[r][c][3]
            + (float)canon[2816 + c];
    size_t rg = (size_t)bm * 64 + r;
    if (flagp[0]) ((float*)out)[rg * 2 + c] = v;
    else          ((bf16_t*)out)[rg * 2 + c] = (bf16_t)v;
  }
}

// ---------------- launch ----------------
extern "C" void kernel_launch(void* const* d_in, const int* in_sizes, int n_in,
                              void* d_out, int out_size, void* d_ws, size_t ws_size,
                              hipStream_t stream) {
  const void* x      = d_in[0];
  const void* thr    = d_in[1];
  const void* w1     = d_in[2];
  const void* b1     = d_in[3];
  const void* w2     = d_in[4];
  const void* b2     = d_in[5];
  const void* w3     = d_in[6];
  const void* b3     = d_in[7];
  const void* w4     = d_in[8];
  const void* b4     = d_in[9];
  const int*  starts = (const int*)d_in[10];

  char* ws = (char*)d_ws;
  bf16_t* embh  = (bf16_t*)(ws + OFF_EMBH);
  float*  simv  = (float*)(ws + OFF_SIM);
  bf16_t* w1abT = (bf16_t*)(ws + OFF_W1ABT);
  bf16_t* w2T   = (bf16_t*)(ws + OFF_W2T);
  bf16_t* w3T   = (bf16_t*)(ws + OFF_W3T);
  float*  C1    = (float*)(ws + OFF_C1);
  bf16_t* h2    = (bf16_t*)(ws + OFF_H2);
  int*    flag  = (int*)(ws + OFF_FLAG);
  bf16_t* canon = (bf16_t*)(ws + OFF_CANON);

  // merged: flag + canon + transposes + (span max-pool / cosine / std / sim)
  prep_embsim_kernel<<<256, 1024, 0, stream>>>(
      (const unsigned short*)x, x, starts, thr,
      w1, w2, w3, b1, b2, b3, w4, b4,
      flag, w1abT, w2T, w3T, canon, embh, simv);

  // C1 = emb @ [W1a | W1b] : [1024,768] x [768,1536] -> fp32
  {
    dim3 g(1024 / 64, 1536 / 128);
    gemm1_kernel<<<g, 256, 0, stream>>>(embh, w1abT, C1);
  }

  // h2 = relu(h1 @ w2 + b2), h1 assembled on the fly (dbuf pipeline)
  {
    dim3 g(NROWS / 128, 2);
    gemm2_fused_kernel<<<g, 512, 0, stream>>>(C1, simv, w2T, canon, h2);
  }

  // h3 = relu(h2 @ w3 + b3); logits = h3 @ w4 + b4 (dbuf pipeline)
  gemm3_fused_kernel<<<NROWS / 64, 256, 0, stream>>>(h2, w3T, canon, flag, d_out);
}

// Round 8
// 229.255 us; speedup vs baseline: 1.3313x; 1.1513x over previous
//
#include <hip/hip_runtime.h>
#include <cstdint>
#include <cstddef>

// ---------------- problem constants ----------------
#define B_    16
#define L_    2048
#define H_    768
#define NE_   64
#define SPAN_ 4
#define NPAIR 2016              // 64*63/2
#define NROWS (B_ * NPAIR)      // 32256 = 252 * 128

typedef __bf16 bf16_t;
typedef __bf16 bf16x8 __attribute__((ext_vector_type(8)));
typedef __bf16 bf16x4 __attribute__((ext_vector_type(4)));
typedef float  floatx4 __attribute__((ext_vector_type(4)));

#define AS1 __attribute__((address_space(1)))
#define AS3 __attribute__((address_space(3)))

// ---------------- ws layout (bytes, all 256-aligned) ----------------
#define OFF_EMBH   ((size_t)3145728)
#define OFF_NRMG   ((size_t)4718592)
#define OFF_SIM    ((size_t)8126464)
#define OFF_W1ABT  ((size_t)8255488)
#define OFF_W2T    ((size_t)10614784)
#define OFF_W3T    ((size_t)11401216)
#define OFF_C1     ((size_t)11663360)
#define OFF_H2     ((size_t)67500032)
#define OFF_FLAG   ((size_t)117045248)
#define OFF_CANON  ((size_t)117045504)
// canon bf16: [0:768) w1row0, [768:1536) b1, [1536:2048) b2,
//             [2048:2304) b3, [2304:2816) w4, [2816:2818) b4

// T2 both-sides swizzle (rule #21): applied to the GLOBAL source byte-in-row
// and identically on the ds_read side (LDS dest stays linear).
#define SWZ(colb, row) ((colb) ^ (((row) & 3) << 4))

__device__ inline bf16_t cvt_elem(const void* p, size_t i, int isf) {
  if (isf) return (bf16_t)(((const float*)p)[i]);
  return ((const bf16_t*)p)[i];
}

// ---------------- K0a: flag + canon + weight transposes + entity gather ----
// grid 256 x 1024 threads, block-stride over 481 units:
//   units 0..63   : gather 16 entities each (1 wave/entity, 12 dims/lane):
//                   span max-pool -> embh (bf16), normalized -> nrm_g (bf16)
//   unit  64      : canon pack + flag store
//   units 65..480 : 64x64 LDS-tiled weight transposes (w1a/w1b/w2/w3)
__global__ __launch_bounds__(1024) void prep_kernel(
    const unsigned short* __restrict__ xu,          // == x, for flag scan
    const void* __restrict__ xv, const int* __restrict__ starts,
    const void* __restrict__ w1, const void* __restrict__ w2,
    const void* __restrict__ w3, const void* __restrict__ b1,
    const void* __restrict__ b2, const void* __restrict__ b3,
    const void* __restrict__ w4, const void* __restrict__ b4,
    int* __restrict__ flagout,
    bf16_t* __restrict__ w1abT, bf16_t* __restrict__ w2T,
    bf16_t* __restrict__ w3T, bf16_t* __restrict__ canon,
    bf16_t* __restrict__ embh, bf16_t* __restrict__ nrm_g) {
  __shared__ bf16_t tile[64][65];
  __shared__ int tot[16];
  int blk = blockIdx.x;
  int t = threadIdx.x;

  // ---- inline dtype flag (uniform across all blocks) ----
  {
    int bad = 0;
    for (int i = t; i < 4096; i += 1024) {
      int e = (xu[i] >> 7) & 0xFF;
      if (e > 133 || (e > 0 && e < 90)) bad++;
    }
    for (int off = 32; off > 0; off >>= 1) bad += __shfl_down(bad, off, 64);
    if ((t & 63) == 0) tot[t >> 6] = bad;
    __syncthreads();
  }
  int sumb = 0;
#pragma unroll
  for (int i = 0; i < 16; i++) sumb += tot[i];
  int isf = (sumb > 200) ? 1 : 0;
  __syncthreads();

  for (int u = blk; u < 481; u += 256) {
    if (u < 64) {
      // ---- gather unit: 16 entities, one wave each, 12 dims/lane ----
      int lane = t & 63;
      int entity = u * 16 + (t >> 6);
      int st = starts[entity];
      int b = entity >> 6;
      size_t off = ((size_t)(b * L_ + st)) * H_;
      int d0 = lane * 12;
      float pool[12];
      float ss = 0.f;
      if (isf) {
        const float* xp = (const float*)xv + off + d0;
#pragma unroll
        for (int k = 0; k < 3; k++) {
          floatx4 r0 = *(const floatx4*)(xp + k * 4);
          floatx4 r1 = *(const floatx4*)(xp + H_ + k * 4);
          floatx4 r2 = *(const floatx4*)(xp + 2 * H_ + k * 4);
          floatx4 r3 = *(const floatx4*)(xp + 3 * H_ + k * 4);
#pragma unroll
          for (int q = 0; q < 4; q++) {
            float v = fmaxf(fmaxf(r0[q], r1[q]), fmaxf(r2[q], r3[q]));
            pool[k * 4 + q] = v;
            ss += v * v;
          }
        }
      } else {
        const bf16_t* xp = (const bf16_t*)xv + off + d0;
#pragma unroll
        for (int k = 0; k < 3; k++) {
          bf16x4 r0 = *(const bf16x4*)(xp + k * 4);
          bf16x4 r1 = *(const bf16x4*)(xp + H_ + k * 4);
          bf16x4 r2 = *(const bf16x4*)(xp + 2 * H_ + k * 4);
          bf16x4 r3 = *(const bf16x4*)(xp + 3 * H_ + k * 4);
#pragma unroll
          for (int q = 0; q < 4; q++) {
            float v = fmaxf(fmaxf((float)r0[q], (float)r1[q]),
                            fmaxf((float)r2[q], (float)r3[q]));
            pool[k * 4 + q] = v;
            ss += v * v;
          }
        }
      }
#pragma unroll
      for (int d = 1; d < 64; d <<= 1) ss += __shfl_xor(ss, d, 64);
      float inv = 1.0f / fmaxf(sqrtf(ss), 1e-8f);
      size_t base = (size_t)entity * 768 + d0;
#pragma unroll
      for (int k = 0; k < 3; k++) {
        bf16x4 op, on;
#pragma unroll
        for (int q = 0; q < 4; q++) {
          op[q] = (bf16_t)pool[k * 4 + q];
          on[q] = (bf16_t)(pool[k * 4 + q] * inv);
        }
        *(bf16x4*)(embh + base + k * 4) = op;
        *(bf16x4*)(nrm_g + base + k * 4) = on;
      }
    } else if (u == 64) {
      // ---- canon + flag ----
      if (t == 0) flagout[0] = isf;
      for (int idx = t; idx < 2818; idx += 1024) {
        if (idx < 768)       canon[idx] = cvt_elem(w1, idx, isf);
        else if (idx < 1536) canon[idx] = cvt_elem(b1, idx - 768, isf);
        else if (idx < 2048) canon[idx] = cvt_elem(b2, idx - 1536, isf);
        else if (idx < 2304) canon[idx] = cvt_elem(b3, idx - 2048, isf);
        else if (idx < 2816) canon[idx] = cvt_elem(w4, idx - 2304, isf);
        else                 canon[idx] = cvt_elem(b4, idx - 2816, isf);
      }
    } else {
      // ---- 64x64 weight transpose ----
      int tix = u - 65;
      const void* src; size_t srcoff; bf16_t* dst; int K, N;
      if (tix < 144)      { src = w1; srcoff = 768;               dst = w1abT;          K = 768; N = 768; }
      else if (tix < 288) { src = w1; srcoff = (size_t)769 * 768; dst = w1abT + 589824; K = 768; N = 768; tix -= 144; }
      else if (tix < 384) { src = w2; srcoff = 0;                 dst = w2T;            K = 768; N = 512; tix -= 288; }
      else                { src = w3; srcoff = 0;                 dst = w3T;            K = 512; N = 256; tix -= 384; }
      int tiles_k = K >> 6;
      int tn_t = tix / tiles_k, tk_t = tix - tn_t * tiles_k;
      int ty = t >> 6, tx = t & 63;
      __syncthreads();          // protect tile buffer across stride iterations
#pragma unroll
      for (int p = 0; p < 4; p++) {
        int kk = tk_t * 64 + p * 16 + ty;
        int nn = tn_t * 64 + tx;
        tile[p * 16 + ty][tx] = cvt_elem(src, srcoff + (size_t)kk * N + nn, isf);
      }
      __syncthreads();
#pragma unroll
      for (int p = 0; p < 4; p++) {
        int nn = tn_t * 64 + p * 16 + ty;
        int kk = tk_t * 64 + tx;
        dst[(size_t)nn * K + kk] = tile[tx][p * 16 + ty];
      }
    }
  }
}

// ---------------- K0b: cosine/std/sim (blocks 0-15) + GEMM1 (16-207) ------
// 208 blocks x 256 threads. cos: load nrm_g rows (L2-hot) into swizzled LDS,
// 4-wave MFMA (wave ti = w, tj = 0..3), std(ddof=1) + sim scatter.
// gemm1: 64x128 tiles, dbuf single-barrier pipeline, C1 fp32 out.
__global__ __launch_bounds__(256) void cosgemm1_kernel(
    const bf16_t* __restrict__ nrm_g, const bf16_t* __restrict__ embh,
    const bf16_t* __restrict__ w1abT, const int* __restrict__ flagp,
    const void* __restrict__ thr_ptr, float* __restrict__ simv,
    float* __restrict__ C1) {
  __shared__ __align__(16) char shb[98304];
  __shared__ float red1[4], red2[4];
  __shared__ float scale_s, thr_s;
  int blk = blockIdx.x;
  int t = threadIdx.x;
  int w = t >> 6, lane = t & 63;
  int quad = lane >> 4, l15 = lane & 15;

  if (blk < 16) {
    // ================= cosine + std + sim =================
    bf16_t* nrm = (bf16_t*)shb;                     // 64 x 768, xor-swizzled
    int b = blk;
    const bf16_t* src = nrm_g + (size_t)b * 64 * 768;
    {
      int lr = t >> 2, c0 = (t & 3) * 192;
      for (int i = 0; i < 24; i++) {
        int col = c0 + i * 8;
        bf16x8 v = *(const bf16x8*)(src + lr * 768 + col);
        *(bf16x8*)((char*)nrm + ((lr * 1536 + col * 2) ^ ((lr & 7) << 4))) = v;
      }
    }
    __syncthreads();

    int rowA = w * 16 + l15;
    int xa = (rowA & 7) << 4;
    floatx4 acc[4] = {};
    for (int k0 = 0; k0 < 768; k0 += 32) {
      int cb = (k0 + quad * 8) * 2;
      bf16x8 aF = *(const bf16x8*)((char*)nrm + ((rowA * 1536 + cb) ^ xa));
#pragma unroll
      for (int tj = 0; tj < 4; tj++) {
        int rb = tj * 16 + l15;
        bf16x8 bF = *(const bf16x8*)((char*)nrm + ((rb * 1536 + cb) ^ ((rb & 7) << 4)));
        acc[tj] = __builtin_amdgcn_mfma_f32_16x16x32_bf16(aF, bF, acc[tj], 0, 0, 0);
      }
    }

    float s1 = 0.f, s2 = 0.f;
#pragma unroll
    for (int tj = 0; tj < 4; tj++)
#pragma unroll
      for (int r = 0; r < 4; r++) { s1 += acc[tj][r]; s2 += acc[tj][r] * acc[tj][r]; }
#pragma unroll
    for (int d = 1; d < 64; d <<= 1) {
      s1 += __shfl_xor(s1, d, 64);
      s2 += __shfl_xor(s2, d, 64);
    }
    if (lane == 0) { red1[w] = s1; red2[w] = s2; }
    __syncthreads();
    if (t == 0) {
      float S1 = red1[0] + red1[1] + red1[2] + red1[3];
      float S2 = red2[0] + red2[1] + red2[2] + red2[3];
      float mean = S1 * (1.0f / 4096.0f);
      float var = (S2 - 4096.0f * mean * mean) * (1.0f / 4095.0f);
      float sd = sqrtf(fmaxf(var, 0.f));
      scale_s = 1.0f / (sd + 1e-5f);
      thr_s = flagp[0] ? *(const float*)thr_ptr : (float)(*(const bf16_t*)thr_ptr);
    }
    __syncthreads();
    float sc = scale_s, th = thr_s;
#pragma unroll
    for (int tj = 0; tj < 4; tj++) {
      int j = tj * 16 + l15;
#pragma unroll
      for (int r = 0; r < 4; r++) {
        int i = w * 16 + quad * 4 + r;
        if (j > i) {
          int p = i * 63 - (i * (i - 1)) / 2 + (j - i - 1);
          simv[b * NPAIR + p] = (acc[tj][r] - th) * sc;
        }
      }
    }
    return;
  }

  // ================= gemm1: 64x128 tile, dbuf pipeline =================
  // LDS layout in shb: A buffers at 0 / 4096, B buffers at 8192 / 16384.
  const int K = 768, N = 1536;
  int bi = blk - 16;
  int bm = bi / 12, bn = bi - bm * 12;
  int wm = w >> 1, wn = w & 1;                     // 2x2 waves, wave = 32x64

  floatx4 acc[2][4] = {};
  const char* Abase = (const char*)(embh + (size_t)bm * 64 * K);
  const char* Bbase = (const char*)(w1abT + (size_t)bn * 128 * K);
  const int rowbytes = K * 2;

  // prologue: stage k-step 0 into buffer 0
  {
    int fo = w * 1024 + lane * 16;
    int row = fo >> 6, colb = fo & 63;
    __builtin_amdgcn_global_load_lds(
        (AS1 char*)(Abase + (size_t)row * rowbytes + SWZ(colb, row)),
        (AS3 char*)(shb + w * 1024), 16, 0, 0);
  }
#pragma unroll
  for (int it = 0; it < 2; it++) {
    int fo = (w * 2 + it) * 1024 + lane * 16;
    int row = fo >> 6, colb = fo & 63;
    __builtin_amdgcn_global_load_lds(
        (AS1 char*)(Bbase + (size_t)row * rowbytes + SWZ(colb, row)),
        (AS3 char*)(shb + 8192 + (w * 2 + it) * 1024), 16, 0, 0);
  }
  __syncthreads();

  for (int kt = 0; kt < 24; ++kt) {
    int cur = kt & 1, nxt = cur ^ 1;
    if (kt < 23) {
      int k1 = (kt + 1) * 32;
      {
        int fo = w * 1024 + lane * 16;
        int row = fo >> 6, colb = fo & 63;
        __builtin_amdgcn_global_load_lds(
            (AS1 char*)(Abase + (size_t)row * rowbytes + k1 * 2 + SWZ(colb, row)),
            (AS3 char*)(shb + nxt * 4096 + w * 1024), 16, 0, 0);
      }
#pragma unroll
      for (int it = 0; it < 2; it++) {
        int fo = (w * 2 + it) * 1024 + lane * 16;
        int row = fo >> 6, colb = fo & 63;
        __builtin_amdgcn_global_load_lds(
            (AS1 char*)(Bbase + (size_t)row * rowbytes + k1 * 2 + SWZ(colb, row)),
            (AS3 char*)(shb + 8192 + nxt * 8192 + (w * 2 + it) * 1024), 16, 0, 0);
      }
    }

    const char* Ac = shb + cur * 4096;
    const char* Bc = shb + 8192 + cur * 8192;
    bf16x8 aF[2], bF[4];
#pragma unroll
    for (int tm = 0; tm < 2; tm++) {
      int ra = wm * 32 + tm * 16 + l15;
      aF[tm] = *((const bf16x8*)(Ac + ra * 64 + SWZ(quad * 16, ra)));
    }
#pragma unroll
    for (int tn = 0; tn < 4; tn++) {
      int rb = wn * 64 + tn * 16 + l15;
      bF[tn] = *((const bf16x8*)(Bc + rb * 64 + SWZ(quad * 16, rb)));
    }
#pragma unroll
    for (int tm = 0; tm < 2; tm++)
#pragma unroll
      for (int tn = 0; tn < 4; tn++)
        acc[tm][tn] = __builtin_amdgcn_mfma_f32_16x16x32_bf16(aF[tm], bF[tn], acc[tm][tn], 0, 0, 0);
    __syncthreads();
  }

#pragma unroll
  for (int tm = 0; tm < 2; tm++) {
    int grow0 = bm * 64 + wm * 32 + tm * 16 + quad * 4;
#pragma unroll
    for (int tn = 0; tn < 4; tn++) {
      int gcol = bn * 128 + wn * 64 + tn * 16 + l15;
#pragma unroll
      for (int r = 0; r < 4; r++)
        C1[(size_t)(grow0 + r) * N + gcol] = acc[tm][tn][r];
    }
  }
}

// ---------------- K2: GEMM2 fused, dbuf single-barrier pipeline ----------
// tile 128 x 256, grid (252,2), 512 thr / 8 waves (64x64 each).
__global__ __launch_bounds__(512, 4) void gemm2_fused_kernel(
    const float* __restrict__ C1, const float* __restrict__ sim,
    const bf16_t* __restrict__ w2T, const bf16_t* __restrict__ canon,
    bf16_t* __restrict__ h2) {
  __shared__ __align__(16) bf16_t Asm[2][128 * 40];  // 2 x 10 KB, padded rows
  __shared__ __align__(16) bf16_t Bsm[2][256 * 32];  // 2 x 16 KB
  __shared__ int   rowI[128], rowJ[128];
  __shared__ float rowS[128];
  __shared__ bf16_t w1s[768], b1s[768];
  __shared__ float b2s[256];
  int bm = blockIdx.x, bn = blockIdx.y;
  int t = threadIdx.x;

  if (t < 128) {
    int r = bm * 128 + t;
    int b = r / NPAIR, p = r - b * NPAIR;
    int i = 0, rem = p;
    while (rem >= 63 - i) { rem -= 63 - i; i++; }
    rowI[t] = b * 64 + i;
    rowJ[t] = b * 64 + i + 1 + rem;
    rowS[t] = sim[r];
  }
  for (int c = t; c < 768; c += 512) { w1s[c] = canon[c]; b1s[c] = canon[768 + c]; }
  if (t < 256) b2s[t] = (float)canon[1536 + bn * 256 + t];
  __syncthreads();

  int w = t >> 6, lane = t & 63;
  int quad = lane >> 4, l15 = lane & 15;
  int wm = w >> 2, wn = w & 3;
  floatx4 acc[4][4] = {};

  const char* Bbase = (const char*)(w2T + (size_t)bn * 256 * 768);

  int arow = t >> 2;             // 0..127
  int acolc = (t & 3) * 8;       // 0,8,16,24
  const float* Ai = C1 + (size_t)rowI[arow] * 1536 + acolc;
  const float* Aj = C1 + (size_t)rowJ[arow] * 1536 + 768 + acolc;
  float s = rowS[arow];

  // ---- prologue: stage k-step 0 into buffer 0 ----
  float4 pi0 = *(const float4*)(Ai);
  float4 pi1 = *(const float4*)(Ai + 4);
  float4 pj0 = *(const float4*)(Aj);
  float4 pj1 = *(const float4*)(Aj + 4);
#pragma unroll
  for (int it = 0; it < 2; it++) {
    int fo = w * 2048 + it * 1024 + lane * 16;
    int row = fo >> 6, colb = fo & 63;
    __builtin_amdgcn_global_load_lds(
        (AS1 char*)(Bbase + (size_t)row * 1536 + SWZ(colb, row)),
        (AS3 char*)((char*)&Bsm[0][0] + w * 2048 + it * 1024),
        16, 0, 0);
  }
  {
    int kc = acolc;
    bf16x8 o;
    const bf16x8 wv8 = *(const bf16x8*)(w1s + kc);
    const bf16x8 bv8 = *(const bf16x8*)(b1s + kc);
    o[0] = (bf16_t)fmaxf(pi0.x + pj0.x + s * (float)wv8[0] + (float)bv8[0], 0.f);
    o[1] = (bf16_t)fmaxf(pi0.y + pj0.y + s * (float)wv8[1] + (float)bv8[1], 0.f);
    o[2] = (bf16_t)fmaxf(pi0.z + pj0.z + s * (float)wv8[2] + (float)bv8[2], 0.f);
    o[3] = (bf16_t)fmaxf(pi0.w + pj0.w + s * (float)wv8[3] + (float)bv8[3], 0.f);
    o[4] = (bf16_t)fmaxf(pi1.x + pj1.x + s * (float)wv8[4] + (float)bv8[4], 0.f);
    o[5] = (bf16_t)fmaxf(pi1.y + pj1.y + s * (float)wv8[5] + (float)bv8[5], 0.f);
    o[6] = (bf16_t)fmaxf(pi1.z + pj1.z + s * (float)wv8[6] + (float)bv8[6], 0.f);
    o[7] = (bf16_t)fmaxf(pi1.w + pj1.w + s * (float)wv8[7] + (float)bv8[7], 0.f);
    *(bf16x8*)(&Asm[0][arow * 40 + acolc]) = o;
  }
  pi0 = *(const float4*)(Ai + 32);
  pi1 = *(const float4*)(Ai + 36);
  pj0 = *(const float4*)(Aj + 32);
  pj1 = *(const float4*)(Aj + 36);
  __syncthreads();

  for (int kt = 0; kt < 24; ++kt) {
    int cur = kt & 1, nxt = cur ^ 1;
    if (kt < 23) {
      int k1 = (kt + 1) * 32;
#pragma unroll
      for (int it = 0; it < 2; it++) {   // stage next B
        int fo = w * 2048 + it * 1024 + lane * 16;
        int row = fo >> 6, colb = fo & 63;
        __builtin_amdgcn_global_load_lds(
            (AS1 char*)(Bbase + (size_t)row * 1536 + k1 * 2 + SWZ(colb, row)),
            (AS3 char*)((char*)&Bsm[nxt][0] + w * 2048 + it * 1024),
            16, 0, 0);
      }
      {  // assemble + ds_write next A
        int kc = k1 + acolc;
        bf16x8 o;
        const bf16x8 wv8 = *(const bf16x8*)(w1s + kc);
        const bf16x8 bv8 = *(const bf16x8*)(b1s + kc);
        o[0] = (bf16_t)fmaxf(pi0.x + pj0.x + s * (float)wv8[0] + (float)bv8[0], 0.f);
        o[1] = (bf16_t)fmaxf(pi0.y + pj0.y + s * (float)wv8[1] + (float)bv8[1], 0.f);
        o[2] = (bf16_t)fmaxf(pi0.z + pj0.z + s * (float)wv8[2] + (float)bv8[2], 0.f);
        o[3] = (bf16_t)fmaxf(pi0.w + pj0.w + s * (float)wv8[3] + (float)bv8[3], 0.f);
        o[4] = (bf16_t)fmaxf(pi1.x + pj1.x + s * (float)wv8[4] + (float)bv8[4], 0.f);
        o[5] = (bf16_t)fmaxf(pi1.y + pj1.y + s * (float)wv8[5] + (float)bv8[5], 0.f);
        o[6] = (bf16_t)fmaxf(pi1.z + pj1.z + s * (float)wv8[6] + (float)bv8[6], 0.f);
        o[7] = (bf16_t)fmaxf(pi1.w + pj1.w + s * (float)wv8[7] + (float)bv8[7], 0.f);
        *(bf16x8*)(&Asm[nxt][arow * 40 + acolc]) = o;
      }
      if (kt < 22) {
        int k2 = (kt + 2) * 32;
        pi0 = *(const float4*)(Ai + k2);
        pi1 = *(const float4*)(Ai + k2 + 4);
        pj0 = *(const float4*)(Aj + k2);
        pj1 = *(const float4*)(Aj + k2 + 4);
      }
    }

    bf16x8 aF[4], bF[4];
#pragma unroll
    for (int tm = 0; tm < 4; tm++)
      aF[tm] = *((const bf16x8*)(&Asm[cur][(wm * 64 + tm * 16 + l15) * 40 + quad * 8]));
#pragma unroll
    for (int tn = 0; tn < 4; tn++) {
      int rb = wn * 64 + tn * 16 + l15;
      bF[tn] = *((const bf16x8*)((const char*)&Bsm[cur][0] + rb * 64 + SWZ(quad * 16, rb)));
    }
#pragma unroll
    for (int tm = 0; tm < 4; tm++)
#pragma unroll
      for (int tn = 0; tn < 4; tn++)
        acc[tm][tn] = __builtin_amdgcn_mfma_f32_16x16x32_bf16(aF[tm], bF[tn], acc[tm][tn], 0, 0, 0);
    __syncthreads();
  }

#pragma unroll
  for (int tm = 0; tm < 4; tm++) {
    int grow0 = bm * 128 + wm * 64 + tm * 16 + quad * 4;
#pragma unroll
    for (int tn = 0; tn < 4; tn++) {
      int lcol = wn * 64 + tn * 16 + l15;
      int gcol = bn * 256 + lcol;
#pragma unroll
      for (int r = 0; r < 4; r++) {
        float v = fmaxf(acc[tm][tn][r] + b2s[lcol], 0.f);
        h2[(size_t)(grow0 + r) * 512 + gcol] = (bf16_t)v;
      }
    }
  }
}

// ---------------- K3: GEMM3 fused, dbuf single-barrier pipeline ----------
// tile 64 x 256 (full N), grid 504, 4 waves (64x64 each, wn=w).
__global__ __launch_bounds__(256) void gemm3_fused_kernel(
    const bf16_t* __restrict__ h2, const bf16_t* __restrict__ w3T,
    const bf16_t* __restrict__ canon, const int* __restrict__ flagp,
    void* __restrict__ out) {
  __shared__ __align__(16) bf16_t Asm[2][64 * 32];   // 2 x 4 KB
  __shared__ __align__(16) bf16_t Bsm[2][256 * 32];  // 2 x 16 KB
  __shared__ float part[64][2][4];                 // [row][c][wave]
  __shared__ float w4s[512];
  __shared__ float b3s[256];
  int bm = blockIdx.x;
  int t = threadIdx.x;
  int w = t >> 6, lane = t & 63;
  int quad = lane >> 4, l15 = lane & 15;

  w4s[t]       = (float)canon[2304 + t];
  w4s[256 + t] = (float)canon[2304 + 256 + t];
  b3s[t]       = (float)canon[2048 + t];

  floatx4 acc[4][4] = {};
  const char* Abase = (const char*)(h2 + (size_t)bm * 64 * 512);
  const char* Bbase = (const char*)w3T;

  {
    int fo = w * 1024 + lane * 16;
    int row = fo >> 6, colb = fo & 63;
    __builtin_amdgcn_global_load_lds(
        (AS1 char*)(Abase + (size_t)row * 1024 + SWZ(colb, row)),
        (AS3 char*)((char*)&Asm[0][0] + w * 1024),
        16, 0, 0);
  }
#pragma unroll
  for (int it = 0; it < 4; it++) {
    int fo = w * 4096 + it * 1024 + lane * 16;
    int row = fo >> 6, colb = fo & 63;
    __builtin_amdgcn_global_load_lds(
        (AS1 char*)(Bbase + (size_t)row * 1024 + SWZ(colb, row)),
        (AS3 char*)((char*)&Bsm[0][0] + w * 4096 + it * 1024),
        16, 0, 0);
  }
  __syncthreads();

  for (int kt = 0; kt < 16; ++kt) {
    int cur = kt & 1, nxt = cur ^ 1;
    if (kt < 15) {
      int k1 = (kt + 1) * 32;
      {
        int fo = w * 1024 + lane * 16;
        int row = fo >> 6, colb = fo & 63;
        __builtin_amdgcn_global_load_lds(
            (AS1 char*)(Abase + (size_t)row * 1024 + k1 * 2 + SWZ(colb, row)),
            (AS3 char*)((char*)&Asm[nxt][0] + w * 1024),
            16, 0, 0);
      }
#pragma unroll
      for (int it = 0; it < 4; it++) {
        int fo = w * 4096 + it * 1024 + lane * 16;
        int row = fo >> 6, colb = fo & 63;
        __builtin_amdgcn_global_load_lds(
            (AS1 char*)(Bbase + (size_t)row * 1024 + k1 * 2 + SWZ(colb, row)),
            (AS3 char*)((char*)&Bsm[nxt][0] + w * 4096 + it * 1024),
            16, 0, 0);
      }
    }

    bf16x8 aF[4], bF[4];
#pragma unroll
    for (int tm = 0; tm < 4; tm++) {
      int ra = tm * 16 + l15;
      aF[tm] = *((const bf16x8*)((const char*)&Asm[cur][0] + ra * 64 + SWZ(quad * 16, ra)));
    }
#pragma unroll
    for (int tn = 0; tn < 4; tn++) {
      int rb = w * 64 + tn * 16 + l15;
      bF[tn] = *((const bf16x8*)((const char*)&Bsm[cur][0] + rb * 64 + SWZ(quad * 16, rb)));
    }
#pragma unroll
    for (int tm = 0; tm < 4; tm++)
#pragma unroll
      for (int tn = 0; tn < 4; tn++)
        acc[tm][tn] = __builtin_amdgcn_mfma_f32_16x16x32_bf16(aF[tm], bF[tn], acc[tm][tn], 0, 0, 0);
    __syncthreads();
  }

#pragma unroll
  for (int tm = 0; tm < 4; tm++) {
#pragma unroll
    for (int reg = 0; reg < 4; reg++) {
      float p0 = 0.f, p1 = 0.f;
#pragma unroll
      for (int tn = 0; tn < 4; tn++) {
        int col = w * 64 + tn * 16 + l15;
        float v = fmaxf(acc[tm][tn][reg] + b3s[col], 0.f);
        p0 += v * w4s[col * 2];
        p1 += v * w4s[col * 2 + 1];
      }
#pragma unroll
      for (int d = 1; d < 16; d <<= 1) {
        p0 += __shfl_xor(p0, d, 64);
        p1 += __shfl_xor(p1, d, 64);
      }
      if (l15 == 0) {
        int r = tm * 16 + quad * 4 + reg;
        part[r][0][w] = p0;
        part[r][1][w] = p1;
      }
    }
  }
  __syncthreads();
  if (t < 128) {
    int r = t >> 1, c = t & 1;
    float v = part[r][c][0] + part[r][c][1] + part[r][c][2] + part[r][c][3]
            + (float)canon[2816 + c];
    size_t rg = (size_t)bm * 64 + r;
    if (flagp[0]) ((float*)out)[rg * 2 + c] = v;
    else          ((bf16_t*)out)[rg * 2 + c] = (bf16_t)v;
  }
}

// ---------------- launch ----------------
extern "C" void kernel_launch(void* const* d_in, const int* in_sizes, int n_in,
                              void* d_out, int out_size, void* d_ws, size_t ws_size,
                              hipStream_t stream) {
  const void* x      = d_in[0];
  const void* thr    = d_in[1];
  const void* w1     = d_in[2];
  const void* b1     = d_in[3];
  const void* w2     = d_in[4];
  const void* b2     = d_in[5];
  const void* w3     = d_in[6];
  const void* b3     = d_in[7];
  const void* w4     = d_in[8];
  const void* b4     = d_in[9];
  const int*  starts = (const int*)d_in[10];

  char* ws = (char*)d_ws;
  bf16_t* embh  = (bf16_t*)(ws + OFF_EMBH);
  bf16_t* nrm_g = (bf16_t*)(ws + OFF_NRMG);
  float*  simv  = (float*)(ws + OFF_SIM);
  bf16_t* w1abT = (bf16_t*)(ws + OFF_W1ABT);
  bf16_t* w2T   = (bf16_t*)(ws + OFF_W2T);
  bf16_t* w3T   = (bf16_t*)(ws + OFF_W3T);
  float*  C1    = (float*)(ws + OFF_C1);
  bf16_t* h2    = (bf16_t*)(ws + OFF_H2);
  int*    flag  = (int*)(ws + OFF_FLAG);
  bf16_t* canon = (bf16_t*)(ws + OFF_CANON);

  // K0a: flag + canon + transposes + balanced entity gather
  prep_kernel<<<256, 1024, 0, stream>>>(
      (const unsigned short*)x, x, starts,
      w1, w2, w3, b1, b2, b3, w4, b4,
      flag, w1abT, w2T, w3T, canon, embh, nrm_g);

  // K0b: cosine/std/sim (16 blocks) + gemm1 C1 = emb @ [W1a|W1b] (192 blocks)
  cosgemm1_kernel<<<208, 256, 0, stream>>>(nrm_g, embh, w1abT, flag, thr,
                                           simv, C1);

  // h2 = relu(h1 @ w2 + b2), h1 assembled on the fly (dbuf pipeline)
  {
    dim3 g(NROWS / 128, 2);
    gemm2_fused_kernel<<<g, 512, 0, stream>>>(C1, simv, w2T, canon, h2);
  }

  // h3 = relu(h2 @ w3 + b3); logits = h3 @ w4 + b4 (dbuf pipeline)
  gemm3_fused_kernel<<<NROWS / 64, 256, 0, stream>>>(h2, w3T, canon, flag, d_out);
}

// Round 9
// 226.708 us; speedup vs baseline: 1.3463x; 1.0112x over previous
//
#include <hip/hip_runtime.h>
#include <cstdint>
#include <cstddef>

// ---------------- problem constants ----------------
#define B_    16
#define L_    2048
#define H_    768
#define NE_   64
#define SPAN_ 4
#define NPAIR 2016              // 64*63/2
#define NROWS (B_ * NPAIR)      // 32256 = 252 * 128

typedef __bf16 bf16_t;
typedef __bf16 bf16x8 __attribute__((ext_vector_type(8)));
typedef __bf16 bf16x4 __attribute__((ext_vector_type(4)));
typedef float  floatx4 __attribute__((ext_vector_type(4)));

#define AS1 __attribute__((address_space(1)))
#define AS3 __attribute__((address_space(3)))

// ---------------- ws layout (bytes, all 256-aligned) ----------------
#define OFF_EMBH   ((size_t)3145728)
#define OFF_NRMG   ((size_t)4718592)
#define OFF_SIM    ((size_t)8126464)
#define OFF_W1ABT  ((size_t)8255488)
#define OFF_W2T    ((size_t)10614784)
#define OFF_W3T    ((size_t)11401216)
#define OFF_C1     ((size_t)11663360)
#define OFF_H2     ((size_t)67500032)
#define OFF_FLAG   ((size_t)117045248)
#define OFF_CANON  ((size_t)117045504)
// canon bf16: [0:768) w1row0, [768:1536) b1, [1536:2048) b2,
//             [2048:2304) b3, [2304:2816) w4, [2816:2818) b4
// C1 is now bf16 [1024][1536] = 3.1 MB (fits one XCD L2 -> faster re-reads)

// T2 both-sides swizzle (rule #21): applied to the GLOBAL source byte-in-row
// and identically on the ds_read side (LDS dest stays linear).
#define SWZ(colb, row) ((colb) ^ (((row) & 3) << 4))

__device__ inline bf16_t cvt_elem(const void* p, size_t i, int isf) {
  if (isf) return (bf16_t)(((const float*)p)[i]);
  return ((const bf16_t*)p)[i];
}

// ---------------- K0a: flag + canon + weight transposes + entity gather ----
// grid 256 x 1024 threads, block-stride over 481 units:
//   units 0..63   : gather 16 entities each (1 wave/entity, 12 dims/lane):
//                   span max-pool -> embh (bf16), normalized -> nrm_g (bf16)
//   unit  64      : canon pack + flag store
//   units 65..480 : 64x64 LDS-tiled weight transposes (w1a/w1b/w2/w3)
__global__ __launch_bounds__(1024) void prep_kernel(
    const unsigned short* __restrict__ xu,          // == x, for flag scan
    const void* __restrict__ xv, const int* __restrict__ starts,
    const void* __restrict__ w1, const void* __restrict__ w2,
    const void* __restrict__ w3, const void* __restrict__ b1,
    const void* __restrict__ b2, const void* __restrict__ b3,
    const void* __restrict__ w4, const void* __restrict__ b4,
    int* __restrict__ flagout,
    bf16_t* __restrict__ w1abT, bf16_t* __restrict__ w2T,
    bf16_t* __restrict__ w3T, bf16_t* __restrict__ canon,
    bf16_t* __restrict__ embh, bf16_t* __restrict__ nrm_g) {
  __shared__ bf16_t tile[64][65];
  __shared__ int tot[16];
  int blk = blockIdx.x;
  int t = threadIdx.x;

  // ---- inline dtype flag (uniform across all blocks) ----
  {
    int bad = 0;
    for (int i = t; i < 4096; i += 1024) {
      int e = (xu[i] >> 7) & 0xFF;
      if (e > 133 || (e > 0 && e < 90)) bad++;
    }
    for (int off = 32; off > 0; off >>= 1) bad += __shfl_down(bad, off, 64);
    if ((t & 63) == 0) tot[t >> 6] = bad;
    __syncthreads();
  }
  int sumb = 0;
#pragma unroll
  for (int i = 0; i < 16; i++) sumb += tot[i];
  int isf = (sumb > 200) ? 1 : 0;
  __syncthreads();

  for (int u = blk; u < 481; u += 256) {
    if (u < 64) {
      // ---- gather unit: 16 entities, one wave each, 12 dims/lane ----
      int lane = t & 63;
      int entity = u * 16 + (t >> 6);
      int st = starts[entity];
      int b = entity >> 6;
      size_t off = ((size_t)(b * L_ + st)) * H_;
      int d0 = lane * 12;
      float pool[12];
      float ss = 0.f;
      if (isf) {
        const float* xp = (const float*)xv + off + d0;
#pragma unroll
        for (int k = 0; k < 3; k++) {
          floatx4 r0 = *(const floatx4*)(xp + k * 4);
          floatx4 r1 = *(const floatx4*)(xp + H_ + k * 4);
          floatx4 r2 = *(const floatx4*)(xp + 2 * H_ + k * 4);
          floatx4 r3 = *(const floatx4*)(xp + 3 * H_ + k * 4);
#pragma unroll
          for (int q = 0; q < 4; q++) {
            float v = fmaxf(fmaxf(r0[q], r1[q]), fmaxf(r2[q], r3[q]));
            pool[k * 4 + q] = v;
            ss += v * v;
          }
        }
      } else {
        const bf16_t* xp = (const bf16_t*)xv + off + d0;
#pragma unroll
        for (int k = 0; k < 3; k++) {
          bf16x4 r0 = *(const bf16x4*)(xp + k * 4);
          bf16x4 r1 = *(const bf16x4*)(xp + H_ + k * 4);
          bf16x4 r2 = *(const bf16x4*)(xp + 2 * H_ + k * 4);
          bf16x4 r3 = *(const bf16x4*)(xp + 3 * H_ + k * 4);
#pragma unroll
          for (int q = 0; q < 4; q++) {
            float v = fmaxf(fmaxf((float)r0[q], (float)r1[q]),
                            fmaxf((float)r2[q], (float)r3[q]));
            pool[k * 4 + q] = v;
            ss += v * v;
          }
        }
      }
#pragma unroll
      for (int d = 1; d < 64; d <<= 1) ss += __shfl_xor(ss, d, 64);
      float inv = 1.0f / fmaxf(sqrtf(ss), 1e-8f);
      size_t base = (size_t)entity * 768 + d0;
#pragma unroll
      for (int k = 0; k < 3; k++) {
        bf16x4 op, on;
#pragma unroll
        for (int q = 0; q < 4; q++) {
          op[q] = (bf16_t)pool[k * 4 + q];
          on[q] = (bf16_t)(pool[k * 4 + q] * inv);
        }
        *(bf16x4*)(embh + base + k * 4) = op;
        *(bf16x4*)(nrm_g + base + k * 4) = on;
      }
    } else if (u == 64) {
      // ---- canon + flag ----
      if (t == 0) flagout[0] = isf;
      for (int idx = t; idx < 2818; idx += 1024) {
        if (idx < 768)       canon[idx] = cvt_elem(w1, idx, isf);
        else if (idx < 1536) canon[idx] = cvt_elem(b1, idx - 768, isf);
        else if (idx < 2048) canon[idx] = cvt_elem(b2, idx - 1536, isf);
        else if (idx < 2304) canon[idx] = cvt_elem(b3, idx - 2048, isf);
        else if (idx < 2816) canon[idx] = cvt_elem(w4, idx - 2304, isf);
        else                 canon[idx] = cvt_elem(b4, idx - 2816, isf);
      }
    } else {
      // ---- 64x64 weight transpose ----
      int tix = u - 65;
      const void* src; size_t srcoff; bf16_t* dst; int K, N;
      if (tix < 144)      { src = w1; srcoff = 768;               dst = w1abT;          K = 768; N = 768; }
      else if (tix < 288) { src = w1; srcoff = (size_t)769 * 768; dst = w1abT + 589824; K = 768; N = 768; tix -= 144; }
      else if (tix < 384) { src = w2; srcoff = 0;                 dst = w2T;            K = 768; N = 512; tix -= 288; }
      else                { src = w3; srcoff = 0;                 dst = w3T;            K = 512; N = 256; tix -= 384; }
      int tiles_k = K >> 6;
      int tn_t = tix / tiles_k, tk_t = tix - tn_t * tiles_k;
      int ty = t >> 6, tx = t & 63;
      __syncthreads();          // protect tile buffer across stride iterations
#pragma unroll
      for (int p = 0; p < 4; p++) {
        int kk = tk_t * 64 + p * 16 + ty;
        int nn = tn_t * 64 + tx;
        tile[p * 16 + ty][tx] = cvt_elem(src, srcoff + (size_t)kk * N + nn, isf);
      }
      __syncthreads();
#pragma unroll
      for (int p = 0; p < 4; p++) {
        int nn = tn_t * 64 + p * 16 + ty;
        int kk = tk_t * 64 + tx;
        dst[(size_t)nn * K + kk] = tile[tx][p * 16 + ty];
      }
    }
  }
}

// ---------------- K0b: cosine/std/sim (blocks 0-15) + GEMM1 (16-207) ------
// 208 blocks x 256 threads. cos: load nrm_g rows (L2-hot) into swizzled LDS,
// 4-wave MFMA (wave ti = w, tj = 0..3), std(ddof=1) + sim scatter.
// gemm1: 64x128 tiles, dbuf single-barrier pipeline, C1 bf16 out.
__global__ __launch_bounds__(256) void cosgemm1_kernel(
    const bf16_t* __restrict__ nrm_g, const bf16_t* __restrict__ embh,
    const bf16_t* __restrict__ w1abT, const int* __restrict__ flagp,
    const void* __restrict__ thr_ptr, float* __restrict__ simv,
    bf16_t* __restrict__ C1) {
  __shared__ __align__(16) char shb[98304];
  __shared__ float red1[4], red2[4];
  __shared__ float scale_s, thr_s;
  int blk = blockIdx.x;
  int t = threadIdx.x;
  int w = t >> 6, lane = t & 63;
  int quad = lane >> 4, l15 = lane & 15;

  if (blk < 16) {
    // ================= cosine + std + sim =================
    bf16_t* nrm = (bf16_t*)shb;                     // 64 x 768, xor-swizzled
    int b = blk;
    const bf16_t* src = nrm_g + (size_t)b * 64 * 768;
    {
      int lr = t >> 2, c0 = (t & 3) * 192;
      for (int i = 0; i < 24; i++) {
        int col = c0 + i * 8;
        bf16x8 v = *(const bf16x8*)(src + lr * 768 + col);
        *(bf16x8*)((char*)nrm + ((lr * 1536 + col * 2) ^ ((lr & 7) << 4))) = v;
      }
    }
    __syncthreads();

    int rowA = w * 16 + l15;
    int xa = (rowA & 7) << 4;
    floatx4 acc[4] = {};
    for (int k0 = 0; k0 < 768; k0 += 32) {
      int cb = (k0 + quad * 8) * 2;
      bf16x8 aF = *(const bf16x8*)((char*)nrm + ((rowA * 1536 + cb) ^ xa));
#pragma unroll
      for (int tj = 0; tj < 4; tj++) {
        int rb = tj * 16 + l15;
        bf16x8 bF = *(const bf16x8*)((char*)nrm + ((rb * 1536 + cb) ^ ((rb & 7) << 4)));
        acc[tj] = __builtin_amdgcn_mfma_f32_16x16x32_bf16(aF, bF, acc[tj], 0, 0, 0);
      }
    }

    float s1 = 0.f, s2 = 0.f;
#pragma unroll
    for (int tj = 0; tj < 4; tj++)
#pragma unroll
      for (int r = 0; r < 4; r++) { s1 += acc[tj][r]; s2 += acc[tj][r] * acc[tj][r]; }
#pragma unroll
    for (int d = 1; d < 64; d <<= 1) {
      s1 += __shfl_xor(s1, d, 64);
      s2 += __shfl_xor(s2, d, 64);
    }
    if (lane == 0) { red1[w] = s1; red2[w] = s2; }
    __syncthreads();
    if (t == 0) {
      float S1 = red1[0] + red1[1] + red1[2] + red1[3];
      float S2 = red2[0] + red2[1] + red2[2] + red2[3];
      float mean = S1 * (1.0f / 4096.0f);
      float var = (S2 - 4096.0f * mean * mean) * (1.0f / 4095.0f);
      float sd = sqrtf(fmaxf(var, 0.f));
      scale_s = 1.0f / (sd + 1e-5f);
      thr_s = flagp[0] ? *(const float*)thr_ptr : (float)(*(const bf16_t*)thr_ptr);
    }
    __syncthreads();
    float sc = scale_s, th = thr_s;
#pragma unroll
    for (int tj = 0; tj < 4; tj++) {
      int j = tj * 16 + l15;
#pragma unroll
      for (int r = 0; r < 4; r++) {
        int i = w * 16 + quad * 4 + r;
        if (j > i) {
          int p = i * 63 - (i * (i - 1)) / 2 + (j - i - 1);
          simv[b * NPAIR + p] = (acc[tj][r] - th) * sc;
        }
      }
    }
    return;
  }

  // ================= gemm1: 64x128 tile, dbuf pipeline =================
  // LDS layout in shb: A buffers at 0 / 4096, B buffers at 8192 / 16384.
  const int K = 768, N = 1536;
  int bi = blk - 16;
  int bm = bi / 12, bn = bi - bm * 12;
  int wm = w >> 1, wn = w & 1;                     // 2x2 waves, wave = 32x64

  floatx4 acc[2][4] = {};
  const char* Abase = (const char*)(embh + (size_t)bm * 64 * K);
  const char* Bbase = (const char*)(w1abT + (size_t)bn * 128 * K);
  const int rowbytes = K * 2;

  // prologue: stage k-step 0 into buffer 0
  {
    int fo = w * 1024 + lane * 16;
    int row = fo >> 6, colb = fo & 63;
    __builtin_amdgcn_global_load_lds(
        (AS1 char*)(Abase + (size_t)row * rowbytes + SWZ(colb, row)),
        (AS3 char*)(shb + w * 1024), 16, 0, 0);
  }
#pragma unroll
  for (int it = 0; it < 2; it++) {
    int fo = (w * 2 + it) * 1024 + lane * 16;
    int row = fo >> 6, colb = fo & 63;
    __builtin_amdgcn_global_load_lds(
        (AS1 char*)(Bbase + (size_t)row * rowbytes + SWZ(colb, row)),
        (AS3 char*)(shb + 8192 + (w * 2 + it) * 1024), 16, 0, 0);
  }
  __syncthreads();

  for (int kt = 0; kt < 24; ++kt) {
    int cur = kt & 1, nxt = cur ^ 1;
    if (kt < 23) {
      int k1 = (kt + 1) * 32;
      {
        int fo = w * 1024 + lane * 16;
        int row = fo >> 6, colb = fo & 63;
        __builtin_amdgcn_global_load_lds(
            (AS1 char*)(Abase + (size_t)row * rowbytes + k1 * 2 + SWZ(colb, row)),
            (AS3 char*)(shb + nxt * 4096 + w * 1024), 16, 0, 0);
      }
#pragma unroll
      for (int it = 0; it < 2; it++) {
        int fo = (w * 2 + it) * 1024 + lane * 16;
        int row = fo >> 6, colb = fo & 63;
        __builtin_amdgcn_global_load_lds(
            (AS1 char*)(Bbase + (size_t)row * rowbytes + k1 * 2 + SWZ(colb, row)),
            (AS3 char*)(shb + 8192 + nxt * 8192 + (w * 2 + it) * 1024), 16, 0, 0);
      }
    }

    const char* Ac = shb + cur * 4096;
    const char* Bc = shb + 8192 + cur * 8192;
    bf16x8 aF[2], bF[4];
#pragma unroll
    for (int tm = 0; tm < 2; tm++) {
      int ra = wm * 32 + tm * 16 + l15;
      aF[tm] = *((const bf16x8*)(Ac + ra * 64 + SWZ(quad * 16, ra)));
    }
#pragma unroll
    for (int tn = 0; tn < 4; tn++) {
      int rb = wn * 64 + tn * 16 + l15;
      bF[tn] = *((const bf16x8*)(Bc + rb * 64 + SWZ(quad * 16, rb)));
    }
#pragma unroll
    for (int tm = 0; tm < 2; tm++)
#pragma unroll
      for (int tn = 0; tn < 4; tn++)
        acc[tm][tn] = __builtin_amdgcn_mfma_f32_16x16x32_bf16(aF[tm], bF[tn], acc[tm][tn], 0, 0, 0);
    __syncthreads();
  }

#pragma unroll
  for (int tm = 0; tm < 2; tm++) {
    int grow0 = bm * 64 + wm * 32 + tm * 16 + quad * 4;
#pragma unroll
    for (int tn = 0; tn < 4; tn++) {
      int gcol = bn * 128 + wn * 64 + tn * 16 + l15;
#pragma unroll
      for (int r = 0; r < 4; r++)
        C1[(size_t)(grow0 + r) * N + gcol] = (bf16_t)acc[tm][tn][r];
    }
  }
}

// ---------------- K2: GEMM2 fused, dbuf pipeline, bf16 C1 ----------------
// tile 128 x 256, grid (252,2), 512 thr / 8 waves (64x64 each).
// C1 is bf16 (3.1 MB, L2-resident): halves the dominant A-gather traffic.
// kt+2 C1 prefetch issued FIRST each iter so the barrier drain never waits
// on it cold.
__global__ __launch_bounds__(512, 4) void gemm2_fused_kernel(
    const bf16_t* __restrict__ C1, const float* __restrict__ sim,
    const bf16_t* __restrict__ w2T, const bf16_t* __restrict__ canon,
    bf16_t* __restrict__ h2) {
  __shared__ __align__(16) bf16_t Asm[2][128 * 40];  // 2 x 10 KB, padded rows
  __shared__ __align__(16) bf16_t Bsm[2][256 * 32];  // 2 x 16 KB
  __shared__ int   rowI[128], rowJ[128];
  __shared__ float rowS[128];
  __shared__ bf16_t w1s[768], b1s[768];
  __shared__ float b2s[256];
  int bm = blockIdx.x, bn = blockIdx.y;
  int t = threadIdx.x;

  if (t < 128) {
    int r = bm * 128 + t;
    int b = r / NPAIR, p = r - b * NPAIR;
    int i = 0, rem = p;
    while (rem >= 63 - i) { rem -= 63 - i; i++; }
    rowI[t] = b * 64 + i;
    rowJ[t] = b * 64 + i + 1 + rem;
    rowS[t] = sim[r];
  }
  for (int c = t; c < 768; c += 512) { w1s[c] = canon[c]; b1s[c] = canon[768 + c]; }
  if (t < 256) b2s[t] = (float)canon[1536 + bn * 256 + t];
  __syncthreads();

  int w = t >> 6, lane = t & 63;
  int quad = lane >> 4, l15 = lane & 15;
  int wm = w >> 2, wn = w & 3;
  floatx4 acc[4][4] = {};

  const char* Bbase = (const char*)(w2T + (size_t)bn * 256 * 768);

  int arow = t >> 2;             // 0..127
  int acolc = (t & 3) * 8;       // 0,8,16,24
  const bf16_t* Ai = C1 + (size_t)rowI[arow] * 1536 + acolc;
  const bf16_t* Aj = C1 + (size_t)rowJ[arow] * 1536 + 768 + acolc;
  float s = rowS[arow];

  // ---- prologue: stage k-step 0 into buffer 0 ----
  bf16x8 pi = *(const bf16x8*)(Ai);
  bf16x8 pj = *(const bf16x8*)(Aj);
#pragma unroll
  for (int it = 0; it < 2; it++) {
    int fo = w * 2048 + it * 1024 + lane * 16;
    int row = fo >> 6, colb = fo & 63;
    __builtin_amdgcn_global_load_lds(
        (AS1 char*)(Bbase + (size_t)row * 1536 + SWZ(colb, row)),
        (AS3 char*)((char*)&Bsm[0][0] + w * 2048 + it * 1024),
        16, 0, 0);
  }
  {
    const bf16x8 wv8 = *(const bf16x8*)(w1s + acolc);
    const bf16x8 bv8 = *(const bf16x8*)(b1s + acolc);
    bf16x8 o;
#pragma unroll
    for (int q = 0; q < 8; q++)
      o[q] = (bf16_t)fmaxf((float)pi[q] + (float)pj[q] + s * (float)wv8[q] + (float)bv8[q], 0.f);
    *(bf16x8*)(&Asm[0][arow * 40 + acolc]) = o;
  }
  pi = *(const bf16x8*)(Ai + 32);
  pj = *(const bf16x8*)(Aj + 32);
  __syncthreads();

  for (int kt = 0; kt < 24; ++kt) {
    int cur = kt & 1, nxt = cur ^ 1;
    if (kt < 23) {
      int k1 = (kt + 1) * 32;
      // far prefetch FIRST (earliest issue -> longest window to complete)
      bf16x8 npi, npj;
      if (kt < 22) {
        int k2 = (kt + 2) * 32;
        npi = *(const bf16x8*)(Ai + k2);
        npj = *(const bf16x8*)(Aj + k2);
      }
#pragma unroll
      for (int it = 0; it < 2; it++) {   // stage next B
        int fo = w * 2048 + it * 1024 + lane * 16;
        int row = fo >> 6, colb = fo & 63;
        __builtin_amdgcn_global_load_lds(
            (AS1 char*)(Bbase + (size_t)row * 1536 + k1 * 2 + SWZ(colb, row)),
            (AS3 char*)((char*)&Bsm[nxt][0] + w * 2048 + it * 1024),
            16, 0, 0);
      }
      {  // assemble + ds_write next A (regs prefetched last iter)
        const bf16x8 wv8 = *(const bf16x8*)(w1s + k1 + acolc);
        const bf16x8 bv8 = *(const bf16x8*)(b1s + k1 + acolc);
        bf16x8 o;
#pragma unroll
        for (int q = 0; q < 8; q++)
          o[q] = (bf16_t)fmaxf((float)pi[q] + (float)pj[q] + s * (float)wv8[q] + (float)bv8[q], 0.f);
        *(bf16x8*)(&Asm[nxt][arow * 40 + acolc]) = o;
      }
      if (kt < 22) { pi = npi; pj = npj; }
    }

    bf16x8 aF[4], bF[4];
#pragma unroll
    for (int tm = 0; tm < 4; tm++)
      aF[tm] = *((const bf16x8*)(&Asm[cur][(wm * 64 + tm * 16 + l15) * 40 + quad * 8]));
#pragma unroll
    for (int tn = 0; tn < 4; tn++) {
      int rb = wn * 64 + tn * 16 + l15;
      bF[tn] = *((const bf16x8*)((const char*)&Bsm[cur][0] + rb * 64 + SWZ(quad * 16, rb)));
    }
#pragma unroll
    for (int tm = 0; tm < 4; tm++)
#pragma unroll
      for (int tn = 0; tn < 4; tn++)
        acc[tm][tn] = __builtin_amdgcn_mfma_f32_16x16x32_bf16(aF[tm], bF[tn], acc[tm][tn], 0, 0, 0);
    __syncthreads();
  }

#pragma unroll
  for (int tm = 0; tm < 4; tm++) {
    int grow0 = bm * 128 + wm * 64 + tm * 16 + quad * 4;
#pragma unroll
    for (int tn = 0; tn < 4; tn++) {
      int lcol = wn * 64 + tn * 16 + l15;
      int gcol = bn * 256 + lcol;
#pragma unroll
      for (int r = 0; r < 4; r++) {
        float v = fmaxf(acc[tm][tn][r] + b2s[lcol], 0.f);
        h2[(size_t)(grow0 + r) * 512 + gcol] = (bf16_t)v;
      }
    }
  }
}

// ---------------- K3: GEMM3 fused, dbuf single-barrier pipeline ----------
// tile 64 x 256 (full N), grid 504, 4 waves (64x64 each, wn=w).
__global__ __launch_bounds__(256) void gemm3_fused_kernel(
    const bf16_t* __restrict__ h2, const bf16_t* __restrict__ w3T,
    const bf16_t* __restrict__ canon, const int* __restrict__ flagp,
    void* __restrict__ out) {
  __shared__ __align__(16) bf16_t Asm[2][64 * 32];   // 2 x 4 KB
  __shared__ __align__(16) bf16_t Bsm[2][256 * 32];  // 2 x 16 KB
  __shared__ float part[64][2][4];                 // [row][c][wave]
  __shared__ float w4s[512];
  __shared__ float b3s[256];
  int bm = blockIdx.x;
  int t = threadIdx.x;
  int w = t >> 6, lane = t & 63;
  int quad = lane >> 4, l15 = lane & 15;

  w4s[t]       = (float)canon[2304 + t];
  w4s[256 + t] = (float)canon[2304 + 256 + t];
  b3s[t]       = (float)canon[2048 + t];

  floatx4 acc[4][4] = {};
  const char* Abase = (const char*)(h2 + (size_t)bm * 64 * 512);
  const char* Bbase = (const char*)w3T;

  {
    int fo = w * 1024 + lane * 16;
    int row = fo >> 6, colb = fo & 63;
    __builtin_amdgcn_global_load_lds(
        (AS1 char*)(Abase + (size_t)row * 1024 + SWZ(colb, row)),
        (AS3 char*)((char*)&Asm[0][0] + w * 1024),
        16, 0, 0);
  }
#pragma unroll
  for (int it = 0; it < 4; it++) {
    int fo = w * 4096 + it * 1024 + lane * 16;
    int row = fo >> 6, colb = fo & 63;
    __builtin_amdgcn_global_load_lds(
        (AS1 char*)(Bbase + (size_t)row * 1024 + SWZ(colb, row)),
        (AS3 char*)((char*)&Bsm[0][0] + w * 4096 + it * 1024),
        16, 0, 0);
  }
  __syncthreads();

  for (int kt = 0; kt < 16; ++kt) {
    int cur = kt & 1, nxt = cur ^ 1;
    if (kt < 15) {
      int k1 = (kt + 1) * 32;
      {
        int fo = w * 1024 + lane * 16;
        int row = fo >> 6, colb = fo & 63;
        __builtin_amdgcn_global_load_lds(
            (AS1 char*)(Abase + (size_t)row * 1024 + k1 * 2 + SWZ(colb, row)),
            (AS3 char*)((char*)&Asm[nxt][0] + w * 1024),
            16, 0, 0);
      }
#pragma unroll
      for (int it = 0; it < 4; it++) {
        int fo = w * 4096 + it * 1024 + lane * 16;
        int row = fo >> 6, colb = fo & 63;
        __builtin_amdgcn_global_load_lds(
            (AS1 char*)(Bbase + (size_t)row * 1024 + k1 * 2 + SWZ(colb, row)),
            (AS3 char*)((char*)&Bsm[nxt][0] + w * 4096 + it * 1024),
            16, 0, 0);
      }
    }

    bf16x8 aF[4], bF[4];
#pragma unroll
    for (int tm = 0; tm < 4; tm++) {
      int ra = tm * 16 + l15;
      aF[tm] = *((const bf16x8*)((const char*)&Asm[cur][0] + ra * 64 + SWZ(quad * 16, ra)));
    }
#pragma unroll
    for (int tn = 0; tn < 4; tn++) {
      int rb = w * 64 + tn * 16 + l15;
      bF[tn] = *((const bf16x8*)((const char*)&Bsm[cur][0] + rb * 64 + SWZ(quad * 16, rb)));
    }
#pragma unroll
    for (int tm = 0; tm < 4; tm++)
#pragma unroll
      for (int tn = 0; tn < 4; tn++)
        acc[tm][tn] = __builtin_amdgcn_mfma_f32_16x16x32_bf16(aF[tm], bF[tn], acc[tm][tn], 0, 0, 0);
    __syncthreads();
  }

#pragma unroll
  for (int tm = 0; tm < 4; tm++) {
#pragma unroll
    for (int reg = 0; reg < 4; reg++) {
      float p0 = 0.f, p1 = 0.f;
#pragma unroll
      for (int tn = 0; tn < 4; tn++) {
        int col = w * 64 + tn * 16 + l15;
        float v = fmaxf(acc[tm][tn][reg] + b3s[col], 0.f);
        p0 += v * w4s[col * 2];
        p1 += v * w4s[col * 2 + 1];
      }
#pragma unroll
      for (int d = 1; d < 16; d <<= 1) {
        p0 += __shfl_xor(p0, d, 64);
        p1 += __shfl_xor(p1, d, 64);
      }
      if (l15 == 0) {
        int r = tm * 16 + quad * 4 + reg;
        part[r][0][w] = p0;
        part[r][1][w] = p1;
      }
    }
  }
  __syncthreads();
  if (t < 128) {
    int r = t >> 1, c = t & 1;
    float v = part[r][c][0] + part[r][c][1] + part[r][c][2] + part[r][c][3]
            + (float)canon[2816 + c];
    size_t rg = (size_t)bm * 64 + r;
    if (flagp[0]) ((float*)out)[rg * 2 + c] = v;
    else          ((bf16_t*)out)[rg * 2 + c] = (bf16_t)v;
  }
}

// ---------------- launch ----------------
extern "C" void kernel_launch(void* const* d_in, const int* in_sizes, int n_in,
                              void* d_out, int out_size, void* d_ws, size_t ws_size,
                              hipStream_t stream) {
  const void* x      = d_in[0];
  const void* thr    = d_in[1];
  const void* w1     = d_in[2];
  const void* b1     = d_in[3];
  const void* w2     = d_in[4];
  const void* b2     = d_in[5];
  const void* w3     = d_in[6];
  const void* b3     = d_in[7];
  const void* w4     = d_in[8];
  const void* b4     = d_in[9];
  const int*  starts = (const int*)d_in[10];

  char* ws = (char*)d_ws;
  bf16_t* embh  = (bf16_t*)(ws + OFF_EMBH);
  bf16_t* nrm_g = (bf16_t*)(ws + OFF_NRMG);
  float*  simv  = (float*)(ws + OFF_SIM);
  bf16_t* w1abT = (bf16_t*)(ws + OFF_W1ABT);
  bf16_t* w2T   = (bf16_t*)(ws + OFF_W2T);
  bf16_t* w3T   = (bf16_t*)(ws + OFF_W3T);
  bf16_t* C1    = (bf16_t*)(ws + OFF_C1);
  bf16_t* h2    = (bf16_t*)(ws + OFF_H2);
  int*    flag  = (int*)(ws + OFF_FLAG);
  bf16_t* canon = (bf16_t*)(ws + OFF_CANON);

  // K0a: flag + canon + transposes + balanced entity gather
  prep_kernel<<<256, 1024, 0, stream>>>(
      (const unsigned short*)x, x, starts,
      w1, w2, w3, b1, b2, b3, w4, b4,
      flag, w1abT, w2T, w3T, canon, embh, nrm_g);

  // K0b: cosine/std/sim (16 blocks) + gemm1 C1 = emb @ [W1a|W1b] (192 blocks)
  cosgemm1_kernel<<<208, 256, 0, stream>>>(nrm_g, embh, w1abT, flag, thr,
                                           simv, C1);

  // h2 = relu(h1 @ w2 + b2), h1 assembled on the fly (dbuf, bf16 C1)
  {
    dim3 g(NROWS / 128, 2);
    gemm2_fused_kernel<<<g, 512, 0, stream>>>(C1, simv, w2T, canon, h2);
  }

  // h3 = relu(h2 @ w3 + b3); logits = h3 @ w4 + b4 (dbuf pipeline)
  gemm3_fused_kernel<<<NROWS / 64, 256, 0, stream>>>(h2, w3T, canon, flag, d_out);
}

// Round 10
// 224.208 us; speedup vs baseline: 1.3613x; 1.0112x over previous
//
#include <hip/hip_runtime.h>
#include <cstdint>
#include <cstddef>

// ---------------- problem constants ----------------
#define B_    16
#define L_    2048
#define H_    768
#define NE_   64
#define SPAN_ 4
#define NPAIR 2016              // 64*63/2
#define NROWS (B_ * NPAIR)      // 32256 = 252 * 128

typedef __bf16 bf16_t;
typedef __bf16 bf16x8 __attribute__((ext_vector_type(8)));
typedef __bf16 bf16x4 __attribute__((ext_vector_type(4)));
typedef float  floatx4 __attribute__((ext_vector_type(4)));

#define AS1 __attribute__((address_space(1)))
#define AS3 __attribute__((address_space(3)))

// ---------------- ws layout (bytes, all 256-aligned) ----------------
#define OFF_EMBH   ((size_t)3145728)
#define OFF_NRMG   ((size_t)4718592)
#define OFF_SIM    ((size_t)8126464)
#define OFF_W1ABT  ((size_t)8255488)
#define OFF_W2T    ((size_t)10614784)
#define OFF_W3T    ((size_t)11401216)
#define OFF_C1     ((size_t)11663360)
#define OFF_H2     ((size_t)67500032)
#define OFF_FLAG   ((size_t)117045248)
#define OFF_CANON  ((size_t)117045504)
// canon bf16: [0:768) w1row0, [768:1536) b1, [1536:2048) b2,
//             [2048:2304) b3, [2304:2816) w4, [2816:2818) b4
// C1 bf16 [1024][1536] = 3.1 MB (L2-resident)

// T2 both-sides swizzle (rule #21): applied to the GLOBAL source byte-in-row
// and identically on the ds_read side (LDS dest stays linear).
#define SWZ(colb, row) ((colb) ^ (((row) & 3) << 4))

__device__ inline bf16_t cvt_elem(const void* p, size_t i, int isf) {
  if (isf) return (bf16_t)(((const float*)p)[i]);
  return ((const bf16_t*)p)[i];
}

// ---------------- K0a: flag + canon + weight transposes + entity gather ----
// grid 256 x 1024 threads, block-stride over 481 units.
__global__ __launch_bounds__(1024) void prep_kernel(
    const unsigned short* __restrict__ xu,
    const void* __restrict__ xv, const int* __restrict__ starts,
    const void* __restrict__ w1, const void* __restrict__ w2,
    const void* __restrict__ w3, const void* __restrict__ b1,
    const void* __restrict__ b2, const void* __restrict__ b3,
    const void* __restrict__ w4, const void* __restrict__ b4,
    int* __restrict__ flagout,
    bf16_t* __restrict__ w1abT, bf16_t* __restrict__ w2T,
    bf16_t* __restrict__ w3T, bf16_t* __restrict__ canon,
    bf16_t* __restrict__ embh, bf16_t* __restrict__ nrm_g) {
  __shared__ bf16_t tile[64][65];
  __shared__ int tot[16];
  int blk = blockIdx.x;
  int t = threadIdx.x;

  {
    int bad = 0;
    for (int i = t; i < 4096; i += 1024) {
      int e = (xu[i] >> 7) & 0xFF;
      if (e > 133 || (e > 0 && e < 90)) bad++;
    }
    for (int off = 32; off > 0; off >>= 1) bad += __shfl_down(bad, off, 64);
    if ((t & 63) == 0) tot[t >> 6] = bad;
    __syncthreads();
  }
  int sumb = 0;
#pragma unroll
  for (int i = 0; i < 16; i++) sumb += tot[i];
  int isf = (sumb > 200) ? 1 : 0;
  __syncthreads();

  for (int u = blk; u < 481; u += 256) {
    if (u < 64) {
      int lane = t & 63;
      int entity = u * 16 + (t >> 6);
      int st = starts[entity];
      int b = entity >> 6;
      size_t off = ((size_t)(b * L_ + st)) * H_;
      int d0 = lane * 12;
      float pool[12];
      float ss = 0.f;
      if (isf) {
        const float* xp = (const float*)xv + off + d0;
#pragma unroll
        for (int k = 0; k < 3; k++) {
          floatx4 r0 = *(const floatx4*)(xp + k * 4);
          floatx4 r1 = *(const floatx4*)(xp + H_ + k * 4);
          floatx4 r2 = *(const floatx4*)(xp + 2 * H_ + k * 4);
          floatx4 r3 = *(const floatx4*)(xp + 3 * H_ + k * 4);
#pragma unroll
          for (int q = 0; q < 4; q++) {
            float v = fmaxf(fmaxf(r0[q], r1[q]), fmaxf(r2[q], r3[q]));
            pool[k * 4 + q] = v;
            ss += v * v;
          }
        }
      } else {
        const bf16_t* xp = (const bf16_t*)xv + off + d0;
#pragma unroll
        for (int k = 0; k < 3; k++) {
          bf16x4 r0 = *(const bf16x4*)(xp + k * 4);
          bf16x4 r1 = *(const bf16x4*)(xp + H_ + k * 4);
          bf16x4 r2 = *(const bf16x4*)(xp + 2 * H_ + k * 4);
          bf16x4 r3 = *(const bf16x4*)(xp + 3 * H_ + k * 4);
#pragma unroll
          for (int q = 0; q < 4; q++) {
            float v = fmaxf(fmaxf((float)r0[q], (float)r1[q]),
                            fmaxf((float)r2[q], (float)r3[q]));
            pool[k * 4 + q] = v;
            ss += v * v;
          }
        }
      }
#pragma unroll
      for (int d = 1; d < 64; d <<= 1) ss += __shfl_xor(ss, d, 64);
      float inv = 1.0f / fmaxf(sqrtf(ss), 1e-8f);
      size_t base = (size_t)entity * 768 + d0;
#pragma unroll
      for (int k = 0; k < 3; k++) {
        bf16x4 op, on;
#pragma unroll
        for (int q = 0; q < 4; q++) {
          op[q] = (bf16_t)pool[k * 4 + q];
          on[q] = (bf16_t)(pool[k * 4 + q] * inv);
        }
        *(bf16x4*)(embh + base + k * 4) = op;
        *(bf16x4*)(nrm_g + base + k * 4) = on;
      }
    } else if (u == 64) {
      if (t == 0) flagout[0] = isf;
      for (int idx = t; idx < 2818; idx += 1024) {
        if (idx < 768)       canon[idx] = cvt_elem(w1, idx, isf);
        else if (idx < 1536) canon[idx] = cvt_elem(b1, idx - 768, isf);
        else if (idx < 2048) canon[idx] = cvt_elem(b2, idx - 1536, isf);
        else if (idx < 2304) canon[idx] = cvt_elem(b3, idx - 2048, isf);
        else if (idx < 2816) canon[idx] = cvt_elem(w4, idx - 2304, isf);
        else                 canon[idx] = cvt_elem(b4, idx - 2816, isf);
      }
    } else {
      int tix = u - 65;
      const void* src; size_t srcoff; bf16_t* dst; int K, N;
      if (tix < 144)      { src = w1; srcoff = 768;               dst = w1abT;          K = 768; N = 768; }
      else if (tix < 288) { src = w1; srcoff = (size_t)769 * 768; dst = w1abT + 589824; K = 768; N = 768; tix -= 144; }
      else if (tix < 384) { src = w2; srcoff = 0;                 dst = w2T;            K = 768; N = 512; tix -= 288; }
      else                { src = w3; srcoff = 0;                 dst = w3T;            K = 512; N = 256; tix -= 384; }
      int tiles_k = K >> 6;
      int tn_t = tix / tiles_k, tk_t = tix - tn_t * tiles_k;
      int ty = t >> 6, tx = t & 63;
      __syncthreads();
#pragma unroll
      for (int p = 0; p < 4; p++) {
        int kk = tk_t * 64 + p * 16 + ty;
        int nn = tn_t * 64 + tx;
        tile[p * 16 + ty][tx] = cvt_elem(src, srcoff + (size_t)kk * N + nn, isf);
      }
      __syncthreads();
#pragma unroll
      for (int p = 0; p < 4; p++) {
        int nn = tn_t * 64 + p * 16 + ty;
        int kk = tk_t * 64 + tx;
        dst[(size_t)nn * K + kk] = tile[tx][p * 16 + ty];
      }
    }
  }
}

// ---------------- K0b: cosine/std/sim (blocks 0-15) + GEMM1 (16-207) ------
__global__ __launch_bounds__(256) void cosgemm1_kernel(
    const bf16_t* __restrict__ nrm_g, const bf16_t* __restrict__ embh,
    const bf16_t* __restrict__ w1abT, const int* __restrict__ flagp,
    const void* __restrict__ thr_ptr, float* __restrict__ simv,
    bf16_t* __restrict__ C1) {
  __shared__ __align__(16) char shb[98304];
  __shared__ float red1[4], red2[4];
  __shared__ float scale_s, thr_s;
  int blk = blockIdx.x;
  int t = threadIdx.x;
  int w = t >> 6, lane = t & 63;
  int quad = lane >> 4, l15 = lane & 15;

  if (blk < 16) {
    bf16_t* nrm = (bf16_t*)shb;                     // 64 x 768, xor-swizzled
    int b = blk;
    const bf16_t* src = nrm_g + (size_t)b * 64 * 768;
    {
      int lr = t >> 2, c0 = (t & 3) * 192;
      for (int i = 0; i < 24; i++) {
        int col = c0 + i * 8;
        bf16x8 v = *(const bf16x8*)(src + lr * 768 + col);
        *(bf16x8*)((char*)nrm + ((lr * 1536 + col * 2) ^ ((lr & 7) << 4))) = v;
      }
    }
    __syncthreads();

    int rowA = w * 16 + l15;
    int xa = (rowA & 7) << 4;
    floatx4 acc[4] = {};
    for (int k0 = 0; k0 < 768; k0 += 32) {
      int cb = (k0 + quad * 8) * 2;
      bf16x8 aF = *(const bf16x8*)((char*)nrm + ((rowA * 1536 + cb) ^ xa));
#pragma unroll
      for (int tj = 0; tj < 4; tj++) {
        int rb = tj * 16 + l15;
        bf16x8 bF = *(const bf16x8*)((char*)nrm + ((rb * 1536 + cb) ^ ((rb & 7) << 4)));
        acc[tj] = __builtin_amdgcn_mfma_f32_16x16x32_bf16(aF, bF, acc[tj], 0, 0, 0);
      }
    }

    float s1 = 0.f, s2 = 0.f;
#pragma unroll
    for (int tj = 0; tj < 4; tj++)
#pragma unroll
      for (int r = 0; r < 4; r++) { s1 += acc[tj][r]; s2 += acc[tj][r] * acc[tj][r]; }
#pragma unroll
    for (int d = 1; d < 64; d <<= 1) {
      s1 += __shfl_xor(s1, d, 64);
      s2 += __shfl_xor(s2, d, 64);
    }
    if (lane == 0) { red1[w] = s1; red2[w] = s2; }
    __syncthreads();
    if (t == 0) {
      float S1 = red1[0] + red1[1] + red1[2] + red1[3];
      float S2 = red2[0] + red2[1] + red2[2] + red2[3];
      float mean = S1 * (1.0f / 4096.0f);
      float var = (S2 - 4096.0f * mean * mean) * (1.0f / 4095.0f);
      float sd = sqrtf(fmaxf(var, 0.f));
      scale_s = 1.0f / (sd + 1e-5f);
      thr_s = flagp[0] ? *(const float*)thr_ptr : (float)(*(const bf16_t*)thr_ptr);
    }
    __syncthreads();
    float sc = scale_s, th = thr_s;
#pragma unroll
    for (int tj = 0; tj < 4; tj++) {
      int j = tj * 16 + l15;
#pragma unroll
      for (int r = 0; r < 4; r++) {
        int i = w * 16 + quad * 4 + r;
        if (j > i) {
          int p = i * 63 - (i * (i - 1)) / 2 + (j - i - 1);
          simv[b * NPAIR + p] = (acc[tj][r] - th) * sc;
        }
      }
    }
    return;
  }

  // ================= gemm1: 64x128 tile, dbuf pipeline =================
  const int K = 768, N = 1536;
  int bi = blk - 16;
  int bm = bi / 12, bn = bi - bm * 12;
  int wm = w >> 1, wn = w & 1;

  floatx4 acc[2][4] = {};
  const char* Abase = (const char*)(embh + (size_t)bm * 64 * K);
  const char* Bbase = (const char*)(w1abT + (size_t)bn * 128 * K);
  const int rowbytes = K * 2;

  {
    int fo = w * 1024 + lane * 16;
    int row = fo >> 6, colb = fo & 63;
    __builtin_amdgcn_global_load_lds(
        (AS1 char*)(Abase + (size_t)row * rowbytes + SWZ(colb, row)),
        (AS3 char*)(shb + w * 1024), 16, 0, 0);
  }
#pragma unroll
  for (int it = 0; it < 2; it++) {
    int fo = (w * 2 + it) * 1024 + lane * 16;
    int row = fo >> 6, colb = fo & 63;
    __builtin_amdgcn_global_load_lds(
        (AS1 char*)(Bbase + (size_t)row * rowbytes + SWZ(colb, row)),
        (AS3 char*)(shb + 8192 + (w * 2 + it) * 1024), 16, 0, 0);
  }
  __syncthreads();

  for (int kt = 0; kt < 24; ++kt) {
    int cur = kt & 1, nxt = cur ^ 1;
    if (kt < 23) {
      int k1 = (kt + 1) * 32;
      {
        int fo = w * 1024 + lane * 16;
        int row = fo >> 6, colb = fo & 63;
        __builtin_amdgcn_global_load_lds(
            (AS1 char*)(Abase + (size_t)row * rowbytes + k1 * 2 + SWZ(colb, row)),
            (AS3 char*)(shb + nxt * 4096 + w * 1024), 16, 0, 0);
      }
#pragma unroll
      for (int it = 0; it < 2; it++) {
        int fo = (w * 2 + it) * 1024 + lane * 16;
        int row = fo >> 6, colb = fo & 63;
        __builtin_amdgcn_global_load_lds(
            (AS1 char*)(Bbase + (size_t)row * rowbytes + k1 * 2 + SWZ(colb, row)),
            (AS3 char*)(shb + 8192 + nxt * 8192 + (w * 2 + it) * 1024), 16, 0, 0);
      }
    }

    const char* Ac = shb + cur * 4096;
    const char* Bc = shb + 8192 + cur * 8192;
    bf16x8 aF[2], bF[4];
#pragma unroll
    for (int tm = 0; tm < 2; tm++) {
      int ra = wm * 32 + tm * 16 + l15;
      aF[tm] = *((const bf16x8*)(Ac + ra * 64 + SWZ(quad * 16, ra)));
    }
#pragma unroll
    for (int tn = 0; tn < 4; tn++) {
      int rb = wn * 64 + tn * 16 + l15;
      bF[tn] = *((const bf16x8*)(Bc + rb * 64 + SWZ(quad * 16, rb)));
    }
#pragma unroll
    for (int tm = 0; tm < 2; tm++)
#pragma unroll
      for (int tn = 0; tn < 4; tn++)
        acc[tm][tn] = __builtin_amdgcn_mfma_f32_16x16x32_bf16(aF[tm], bF[tn], acc[tm][tn], 0, 0, 0);
    __syncthreads();
  }

#pragma unroll
  for (int tm = 0; tm < 2; tm++) {
    int grow0 = bm * 64 + wm * 32 + tm * 16 + quad * 4;
#pragma unroll
    for (int tn = 0; tn < 4; tn++) {
      int gcol = bn * 128 + wn * 64 + tn * 16 + l15;
#pragma unroll
      for (int r = 0; r < 4; r++)
        C1[(size_t)(grow0 + r) * N + gcol] = (bf16_t)acc[tm][tn][r];
    }
  }
}

// ---------------- K2: GEMM2, 3-deep B pipeline + counted waits -----------
// tile 128 x 256, grid (252,2), 512 thr / 8 waves (64x64 each).
// B triple-buffered: step s staged at iter s-2 -> 2-iteration landing window.
// C1 reg-loads issued BETWEEN B[s-1] and B[s]: compiler's auto-wait before
// consuming C1[kt+1] retires exactly B[kt] (vmcnt oldest-first, m135) without
// draining the newer B loads. Raw s_barrier (no implicit vmcnt(0) drain).
__global__ __launch_bounds__(512, 4) void gemm2_fused_kernel(
    const bf16_t* __restrict__ C1, const float* __restrict__ sim,
    const bf16_t* __restrict__ w2T, const bf16_t* __restrict__ canon,
    bf16_t* __restrict__ h2) {
  __shared__ __align__(16) bf16_t Asm[2][128 * 40];  // 20 KB, padded rows
  __shared__ __align__(16) bf16_t Bsm[3][256 * 32];  // 48 KB, 3-deep
  __shared__ int   rowI[128], rowJ[128];
  __shared__ float rowS[128];
  __shared__ bf16_t w1s[768], b1s[768];
  __shared__ float b2s[256];
  int bm = blockIdx.x, bn = blockIdx.y;
  int t = threadIdx.x;

  if (t < 128) {
    int r = bm * 128 + t;
    int b = r / NPAIR, p = r - b * NPAIR;
    int i = 0, rem = p;
    while (rem >= 63 - i) { rem -= 63 - i; i++; }
    rowI[t] = b * 64 + i;
    rowJ[t] = b * 64 + i + 1 + rem;
    rowS[t] = sim[r];
  }
  for (int c = t; c < 768; c += 512) { w1s[c] = canon[c]; b1s[c] = canon[768 + c]; }
  if (t < 256) b2s[t] = (float)canon[1536 + bn * 256 + t];
  __syncthreads();

  int w = t >> 6, lane = t & 63;
  int quad = lane >> 4, l15 = lane & 15;
  int wm = w >> 2, wn = w & 3;
  floatx4 acc[4][4] = {};

  const char* Bbase = (const char*)(w2T + (size_t)bn * 256 * 768);

  int arow = t >> 2;             // 0..127
  int acolc = (t & 3) * 8;       // 0,8,16,24
  const bf16_t* Ai = C1 + (size_t)rowI[arow] * 1536 + acolc;
  const bf16_t* Aj = C1 + (size_t)rowJ[arow] * 1536 + 768 + acolc;
  float s = rowS[arow];

#define G2_STAGE_B(sidx)                                                      \
  {                                                                           \
    _Pragma("unroll")                                                         \
    for (int it = 0; it < 2; it++) {                                          \
      int fo = w * 2048 + it * 1024 + lane * 16;                              \
      int row = fo >> 6, colb = fo & 63;                                      \
      __builtin_amdgcn_global_load_lds(                                       \
          (AS1 char*)(Bbase + (size_t)row * 1536 + (sidx) * 64 + SWZ(colb, row)), \
          (AS3 char*)((char*)&Bsm[(sidx) % 3][0] + w * 2048 + it * 1024),     \
          16, 0, 0);                                                          \
    }                                                                         \
  }

  // ---- prologue ----
  bf16x8 pi = *(const bf16x8*)(Ai);          // C1[0]
  bf16x8 pj = *(const bf16x8*)(Aj);
  {
    const bf16x8 wv8 = *(const bf16x8*)(w1s + acolc);
    const bf16x8 bv8 = *(const bf16x8*)(b1s + acolc);
    bf16x8 o;
#pragma unroll
    for (int q = 0; q < 8; q++)
      o[q] = (bf16_t)fmaxf((float)pi[q] + (float)pj[q] + s * (float)wv8[q] + (float)bv8[q], 0.f);
    *(bf16x8*)(&Asm[0][arow * 40 + acolc]) = o;     // A[0]
  }
  G2_STAGE_B(0);
  pi = *(const bf16x8*)(Ai + 32);            // C1[1] (after B[0], before B[1])
  pj = *(const bf16x8*)(Aj + 32);
  G2_STAGE_B(1);
  asm volatile("s_waitcnt lgkmcnt(0)" ::: "memory");   // A[0] write visible
  __builtin_amdgcn_sched_barrier(0);
  __builtin_amdgcn_s_barrier();

  bf16x8 npi, npj;
  for (int kt = 0; kt < 24; ++kt) {
    if (kt + 2 < 24) {
      int s2 = kt + 2;
      npi = *(const bf16x8*)(Ai + s2 * 32);  // C1[kt+2] FIRST (before B[kt+2])
      npj = *(const bf16x8*)(Aj + s2 * 32);
      G2_STAGE_B(s2);
    }
    if (kt + 1 < 24) {
      // consumes C1[kt+1] -> compiler's vmcnt wait retires B[kt] (oldest-first)
      const bf16x8 wv8 = *(const bf16x8*)(w1s + (kt + 1) * 32 + acolc);
      const bf16x8 bv8 = *(const bf16x8*)(b1s + (kt + 1) * 32 + acolc);
      bf16x8 o;
#pragma unroll
      for (int q = 0; q < 8; q++)
        o[q] = (bf16_t)fmaxf((float)pi[q] + (float)pj[q] + s * (float)wv8[q] + (float)bv8[q], 0.f);
      *(bf16x8*)(&Asm[(kt + 1) & 1][arow * 40 + acolc]) = o;
      pi = npi; pj = npj;
    }
    asm volatile("s_waitcnt lgkmcnt(0)" ::: "memory");   // A write visible
    if (kt == 23) asm volatile("s_waitcnt vmcnt(0)" ::: "memory");
    __builtin_amdgcn_sched_barrier(0);
    __builtin_amdgcn_s_barrier();                        // raw: no vmem drain

    bf16x8 aF[4], bF[4];
#pragma unroll
    for (int tm = 0; tm < 4; tm++)
      aF[tm] = *((const bf16x8*)(&Asm[kt & 1][(wm * 64 + tm * 16 + l15) * 40 + quad * 8]));
#pragma unroll
    for (int tn = 0; tn < 4; tn++) {
      int rb = wn * 64 + tn * 16 + l15;
      bF[tn] = *((const bf16x8*)((const char*)&Bsm[kt % 3][0] + rb * 64 + SWZ(quad * 16, rb)));
    }
#pragma unroll
    for (int tm = 0; tm < 4; tm++)
#pragma unroll
      for (int tn = 0; tn < 4; tn++)
        acc[tm][tn] = __builtin_amdgcn_mfma_f32_16x16x32_bf16(aF[tm], bF[tn], acc[tm][tn], 0, 0, 0);
    __builtin_amdgcn_s_barrier();                        // WAR guard (raw)
  }
#undef G2_STAGE_B

#pragma unroll
  for (int tm = 0; tm < 4; tm++) {
    int grow0 = bm * 128 + wm * 64 + tm * 16 + quad * 4;
#pragma unroll
    for (int tn = 0; tn < 4; tn++) {
      int lcol = wn * 64 + tn * 16 + l15;
      int gcol = bn * 256 + lcol;
#pragma unroll
      for (int r = 0; r < 4; r++) {
        float v = fmaxf(acc[tm][tn][r] + b2s[lcol], 0.f);
        h2[(size_t)(grow0 + r) * 512 + gcol] = (bf16_t)v;
      }
    }
  }
}

// ---------------- K3: GEMM3, 3-deep A+B pipeline + counted vmcnt ---------
// tile 64 x 256 (full N), grid 504, 4 waves. 5 gload_lds/thread/step.
// Step s staged at iter s-2; wait vmcnt(10) keeps the 2 newest steps (10 ops)
// in flight while draining step kt (oldest-first, m135).
__global__ __launch_bounds__(256) void gemm3_fused_kernel(
    const bf16_t* __restrict__ h2, const bf16_t* __restrict__ w3T,
    const bf16_t* __restrict__ canon, const int* __restrict__ flagp,
    void* __restrict__ out) {
  __shared__ __align__(16) bf16_t Asm[3][64 * 32];   // 12 KB, 3-deep
  __shared__ __align__(16) bf16_t Bsm[3][256 * 32];  // 48 KB, 3-deep
  __shared__ float part[64][2][4];
  __shared__ float w4s[512];
  __shared__ float b3s[256];
  int bm = blockIdx.x;
  int t = threadIdx.x;
  int w = t >> 6, lane = t & 63;
  int quad = lane >> 4, l15 = lane & 15;

  w4s[t]       = (float)canon[2304 + t];
  w4s[256 + t] = (float)canon[2304 + 256 + t];
  b3s[t]       = (float)canon[2048 + t];
  __syncthreads();

  floatx4 acc[4][4] = {};
  const char* Abase = (const char*)(h2 + (size_t)bm * 64 * 512);
  const char* Bbase = (const char*)w3T;

#define G3_STAGE(sidx)                                                        \
  {                                                                           \
    {                                                                         \
      int fo = w * 1024 + lane * 16;                                          \
      int row = fo >> 6, colb = fo & 63;                                      \
      __builtin_amdgcn_global_load_lds(                                       \
          (AS1 char*)(Abase + (size_t)row * 1024 + (sidx) * 64 + SWZ(colb, row)), \
          (AS3 char*)((char*)&Asm[(sidx) % 3][0] + w * 1024), 16, 0, 0);      \
    }                                                                         \
    _Pragma("unroll")                                                         \
    for (int it = 0; it < 4; it++) {                                          \
      int fo = w * 4096 + it * 1024 + lane * 16;                              \
      int row = fo >> 6, colb = fo & 63;                                      \
      __builtin_amdgcn_global_load_lds(                                       \
          (AS1 char*)(Bbase + (size_t)row * 1024 + (sidx) * 64 + SWZ(colb, row)), \
          (AS3 char*)((char*)&Bsm[(sidx) % 3][0] + w * 4096 + it * 1024),     \
          16, 0, 0);                                                          \
    }                                                                         \
  }

  // prologue: stage steps 0 and 1 (10 loads in flight)
  G3_STAGE(0);
  G3_STAGE(1);
  asm volatile("s_waitcnt vmcnt(5)" ::: "memory");   // step 0 landed
  __builtin_amdgcn_sched_barrier(0);
  __builtin_amdgcn_s_barrier();

  for (int kt = 0; kt < 16; ++kt) {
    if (kt + 2 < 16) G3_STAGE(kt + 2);
    if (kt < 14)       asm volatile("s_waitcnt vmcnt(10)" ::: "memory");
    else if (kt == 14) asm volatile("s_waitcnt vmcnt(5)" ::: "memory");
    else               asm volatile("s_waitcnt vmcnt(0)" ::: "memory");
    __builtin_amdgcn_sched_barrier(0);
    __builtin_amdgcn_s_barrier();                    // raw: step kt visible

    bf16x8 aF[4], bF[4];
#pragma unroll
    for (int tm = 0; tm < 4; tm++) {
      int ra = tm * 16 + l15;
      aF[tm] = *((const bf16x8*)((const char*)&Asm[kt % 3][0] + ra * 64 + SWZ(quad * 16, ra)));
    }
#pragma unroll
    for (int tn = 0; tn < 4; tn++) {
      int rb = w * 64 + tn * 16 + l15;
      bF[tn] = *((const bf16x8*)((const char*)&Bsm[kt % 3][0] + rb * 64 + SWZ(quad * 16, rb)));
    }
#pragma unroll
    for (int tm = 0; tm < 4; tm++)
#pragma unroll
      for (int tn = 0; tn < 4; tn++)
        acc[tm][tn] = __builtin_amdgcn_mfma_f32_16x16x32_bf16(aF[tm], bF[tn], acc[tm][tn], 0, 0, 0);
    __builtin_amdgcn_s_barrier();                    // WAR guard (raw)
  }
#undef G3_STAGE

#pragma unroll
  for (int tm = 0; tm < 4; tm++) {
#pragma unroll
    for (int reg = 0; reg < 4; reg++) {
      float p0 = 0.f, p1 = 0.f;
#pragma unroll
      for (int tn = 0; tn < 4; tn++) {
        int col = w * 64 + tn * 16 + l15;
        float v = fmaxf(acc[tm][tn][reg] + b3s[col], 0.f);
        p0 += v * w4s[col * 2];
        p1 += v * w4s[col * 2 + 1];
      }
#pragma unroll
      for (int d = 1; d < 16; d <<= 1) {
        p0 += __shfl_xor(p0, d, 64);
        p1 += __shfl_xor(p1, d, 64);
      }
      if (l15 == 0) {
        int r = tm * 16 + quad * 4 + reg;
        part[r][0][w] = p0;
        part[r][1][w] = p1;
      }
    }
  }
  __syncthreads();
  if (t < 128) {
    int r = t >> 1, c = t & 1;
    float v = part[r][c][0] + part[r][c][1] + part[r][c][2] + part[r][c][3]
            + (float)canon[2816 + c];
    size_t rg = (size_t)bm * 64 + r;
    if (flagp[0]) ((float*)out)[rg * 2 + c] = v;
    else          ((bf16_t*)out)[rg * 2 + c] = (bf16_t)v;
  }
}

// ---------------- launch ----------------
extern "C" void kernel_launch(void* const* d_in, const int* in_sizes, int n_in,
                              void* d_out, int out_size, void* d_ws, size_t ws_size,
                              hipStream_t stream) {
  const void* x      = d_in[0];
  const void* thr    = d_in[1];
  const void* w1     = d_in[2];
  const void* b1     = d_in[3];
  const void* w2     = d_in[4];
  const void* b2     = d_in[5];
  const void* w3     = d_in[6];
  const void* b3     = d_in[7];
  const void* w4     = d_in[8];
  const void* b4     = d_in[9];
  const int*  starts = (const int*)d_in[10];

  char* ws = (char*)d_ws;
  bf16_t* embh  = (bf16_t*)(ws + OFF_EMBH);
  bf16_t* nrm_g = (bf16_t*)(ws + OFF_NRMG);
  float*  simv  = (float*)(ws + OFF_SIM);
  bf16_t* w1abT = (bf16_t*)(ws + OFF_W1ABT);
  bf16_t* w2T   = (bf16_t*)(ws + OFF_W2T);
  bf16_t* w3T   = (bf16_t*)(ws + OFF_W3T);
  bf16_t* C1    = (bf16_t*)(ws + OFF_C1);
  bf16_t* h2    = (bf16_t*)(ws + OFF_H2);
  int*    flag  = (int*)(ws + OFF_FLAG);
  bf16_t* canon = (bf16_t*)(ws + OFF_CANON);

  // K0a: flag + canon + transposes + balanced entity gather
  prep_kernel<<<256, 1024, 0, stream>>>(
      (const unsigned short*)x, x, starts,
      w1, w2, w3, b1, b2, b3, w4, b4,
      flag, w1abT, w2T, w3T, canon, embh, nrm_g);

  // K0b: cosine/std/sim (16 blocks) + gemm1 C1 = emb @ [W1a|W1b] (192 blocks)
  cosgemm1_kernel<<<208, 256, 0, stream>>>(nrm_g, embh, w1abT, flag, thr,
                                           simv, C1);

  // h2 = relu(h1 @ w2 + b2), 3-deep B pipeline
  {
    dim3 g(NROWS / 128, 2);
    gemm2_fused_kernel<<<g, 512, 0, stream>>>(C1, simv, w2T, canon, h2);
  }

  // h3 = relu(h2 @ w3 + b3); logits = h3 @ w4 + b4, 3-deep A+B pipeline
  gemm3_fused_kernel<<<NROWS / 64, 256, 0, stream>>>(h2, w3T, canon, flag, d_out);
}